// Round 10
// baseline (432.909 us; speedup 1.0000x reference)
//
#include <hip/hip_runtime.h>
#include <hip/hip_bf16.h>

// Problem constants: B=4, T=2048, D=512, H=8, DK=64
#define T_SEQ 2048
#define N_TOK 4194304   // 4 * 2048 * 512 elements per [B,T,D] tensor
#define W_ELEM 262144   // 512*512

// Inputs: FLOAT32. Output: FLOAT32, (e2s, s2e) concat.
// ws (fused path, 48 MB): Q1,K1 [B,T,512] bf16; Vt1 [B,512,T] bf16; Q2,K2,Vt2.
// AO aliases Q per direction. Fallback (<48 MB ws): 24 MB, sequential.
// Big path: d_out doubles as scratch (skel,sens bf16; 6 proj W bf16; bias
// floats) until out_fused runs (strict stream order; out_fused reads only
// AO bf16 from ws + fp32 Wo from d_in).

typedef float f32x4  __attribute__((ext_vector_type(4)));
typedef short bf16x8 __attribute__((ext_vector_type(8)));
typedef int   i32x4  __attribute__((ext_vector_type(4)));

// 1.5/sqrt(64) * log2(e): attention logits are produced in log2 domain so
// softmax uses bare v_exp_f32 (exp2) with no per-element multiply.
#define SCALE_Q 0.27050532f

__device__ __forceinline__ unsigned short f2b(float f) {
    __hip_bfloat16 h = __float2bfloat16(f);
    return *reinterpret_cast<unsigned short*>(&h);
}

__device__ __forceinline__ int pack2bf(float lo, float hi) {
    return ((int)f2b(hi) << 16) | (int)f2b(lo);
}

__device__ __forceinline__ bf16x8 ldg8(const unsigned short* p) {
    union { int4 i; bf16x8 b; } u;
    u.i = *reinterpret_cast<const int4*>(p);
    return u.b;
}

__device__ __forceinline__ float fexp2(float x) {
#if __has_builtin(__builtin_amdgcn_exp2f)
    return __builtin_amdgcn_exp2f(x);
#else
    return exp2f(x);
#endif
}

// non-temporal 16B stores via ext-vector types (the builtin rejects HIP's
// class-type int4/float4). Bypass L2 for write-once C streams.
__device__ __forceinline__ void nt_store_i4(void* p, const void* src) {
    __builtin_nontemporal_store(*reinterpret_cast<const i32x4*>(src),
                                reinterpret_cast<i32x4*>(p));
}
__device__ __forceinline__ void nt_store_f4(void* p, const void* src) {
    __builtin_nontemporal_store(*reinterpret_cast<const f32x4*>(src),
                                reinterpret_cast<f32x4*>(p));
}

// async global->LDS DMA, 16B per lane; LDS dest = wave-uniform base + lane*16
typedef unsigned int u32_g __attribute__((address_space(1)));
typedef unsigned int u32_l __attribute__((address_space(3)));
__device__ __forceinline__ void gload_lds16(const void* g, void* l) {
    __builtin_amdgcn_global_load_lds((const u32_g*)g, (u32_l*)l, 16, 0, 0);
}

// ---------------------------------------------------------------------------
// mask -> additive float bias precompute: dst = [2][B][T_SEQ] floats (64 KB).
// dir0 <- mask_sens, dir1 <- mask_skel.
// ---------------------------------------------------------------------------
__global__ __launch_bounds__(256)
void prep_bias(const int* __restrict__ ms, const int* __restrict__ mk,
               float* __restrict__ dst)
{
    const int i = (blockIdx.x * 256 + threadIdx.x) * 8;   // 16384 total
    const int* m = (i >> 13) ? mk : ms;
    const int rem = i & 8191;
    const int4 a = *reinterpret_cast<const int4*>(&m[rem]);
    const int4 b = *reinterpret_cast<const int4*>(&m[rem + 4]);
    float4 f0, f1;
    f0.x = a.x ? 0.0f : -3e38f; f0.y = a.y ? 0.0f : -3e38f;
    f0.z = a.z ? 0.0f : -3e38f; f0.w = a.w ? 0.0f : -3e38f;
    f1.x = b.x ? 0.0f : -3e38f; f1.y = b.y ? 0.0f : -3e38f;
    f1.z = b.z ? 0.0f : -3e38f; f1.w = b.w ? 0.0f : -3e38f;
    *reinterpret_cast<float4*>(&dst[i])     = f0;
    *reinterpret_cast<float4*>(&dst[i + 4]) = f1;
}

// ---------------------------------------------------------------------------
// fp32 -> bf16 pre-conversion, exact 1D grid (4864 blocks):
// [0,2048) skel, [2048,4096) sens, then 6 x 128 blocks for proj weights.
// dst layout: [skel 4M][sens 4M][W0..W5 x 256K] shorts (19 MB).
// ---------------------------------------------------------------------------
__global__ __launch_bounds__(256)
void to_bf16(const float* __restrict__ s0, const float* __restrict__ s1,
             const float* __restrict__ w0, const float* __restrict__ w1,
             const float* __restrict__ w2, const float* __restrict__ w3,
             const float* __restrict__ w4, const float* __restrict__ w5,
             unsigned short* __restrict__ dst)
{
    const int bid = blockIdx.x;
    int y, x;
    if (bid < 4096) { y = bid >> 11; x = bid & 2047; }
    else { const int t = bid - 4096; y = 2 + (t >> 7); x = t & 127; }
    const float* src;
    size_t off;
    switch (y) {
        case 0: src = s0; off = 0;      break;
        case 1: src = s1; off = N_TOK;  break;
        case 2: src = w0; off = 2 * (size_t)N_TOK;              break;
        case 3: src = w1; off = 2 * (size_t)N_TOK + 1 * W_ELEM; break;
        case 4: src = w2; off = 2 * (size_t)N_TOK + 2 * W_ELEM; break;
        case 5: src = w3; off = 2 * (size_t)N_TOK + 3 * W_ELEM; break;
        case 6: src = w4; off = 2 * (size_t)N_TOK + 4 * W_ELEM; break;
        default: src = w5; off = 2 * (size_t)N_TOK + 5 * W_ELEM; break;
    }
    const int idx = (x * 256 + threadIdx.x) * 8;
    const float4 a = *reinterpret_cast<const float4*>(src + idx);
    const float4 b = *reinterpret_cast<const float4*>(src + idx + 4);
    int4 o;
    o.x = pack2bf(a.x, a.y); o.y = pack2bf(a.z, a.w);
    o.z = pack2bf(b.x, b.y); o.w = pack2bf(b.z, b.w);
    *reinterpret_cast<int4*>(dst + off + idx) = o;
}

// ---------------------------------------------------------------------------
// Shared MFMA-GEMM tile machinery (fallback proj + fallback out_proj).
// ---------------------------------------------------------------------------
#define MF_SETUP                                                               \
    __shared__ short Asm[64][72];                                              \
    __shared__ short Wsm[64][72];                                              \
    const int tid  = threadIdx.x;                                              \
    const int lane = tid & 63;                                                 \
    const int w4   = tid >> 6;                                                 \
    const int nl   = lane & 15;                                                \
    const int quad = lane >> 4;                                                \
    const int n0 = blockIdx.x * 64;                                            \
    const int m0 = blockIdx.y * 64;                                            \
    const int arow = tid >> 2;                                                 \
    const int acol = (tid & 3) * 16;                                           \
    f32x4 acc[4] = {};

#define MF_WRITE_W                                                             \
    {                                                                          \
        int4 x;                                                                \
        x.x = pack2bf(wv[0].x, wv[0].y); x.y = pack2bf(wv[0].z, wv[0].w);      \
        x.z = pack2bf(wv[1].x, wv[1].y); x.w = pack2bf(wv[1].z, wv[1].w);      \
        *reinterpret_cast<int4*>(&Wsm[arow][acol]) = x;                        \
        x.x = pack2bf(wv[2].x, wv[2].y); x.y = pack2bf(wv[2].z, wv[2].w);      \
        x.z = pack2bf(wv[3].x, wv[3].y); x.w = pack2bf(wv[3].z, wv[3].w);      \
        *reinterpret_cast<int4*>(&Wsm[arow][acol + 8]) = x;                    \
    }

#define MF_MMA_LOOP                                                            \
    _Pragma("unroll")                                                          \
    for (int kc = 0; kc < 2; ++kc) {                                           \
        const bf16x8 a = *reinterpret_cast<const bf16x8*>(                     \
            &Asm[w4 * 16 + nl][kc * 32 + quad * 8]);                           \
        _Pragma("unroll")                                                      \
        for (int c = 0; c < 4; ++c) {                                          \
            const bf16x8 bf = *reinterpret_cast<const bf16x8*>(                \
                &Wsm[c * 16 + nl][kc * 32 + quad * 8]);                        \
            acc[c] = __builtin_amdgcn_mfma_f32_16x16x32_bf16(a, bf, acc[c],    \
                                                             0, 0, 0);         \
        }                                                                      \
    }

#define MF_CWRITE_PROJ                                                         \
    if (!trans) {                                                              \
        _Pragma("unroll")                                                      \
        for (int c = 0; c < 4; ++c)                                            \
            _Pragma("unroll")                                                  \
            for (int r = 0; r < 4; ++r)                                        \
                C[(size_t)(m0 + w4 * 16 + quad * 4 + r) * 512 + n0 + c * 16 + nl] = \
                    f2b(acc[c][r] * alpha);                                    \
    } else {                                                                   \
        const int b  = m0 >> 11;                                               \
        const int t0 = (m0 & 2047) + w4 * 16 + quad * 4;                       \
        _Pragma("unroll")                                                      \
        for (int c = 0; c < 4; ++c) {                                          \
            const int n = n0 + c * 16 + nl;                                    \
            ushort4 o;                                                         \
            o.x = f2b(acc[c][0]);                                              \
            o.y = f2b(acc[c][1]);                                              \
            o.z = f2b(acc[c][2]);                                              \
            o.w = f2b(acc[c][3]);                                              \
            *reinterpret_cast<ushort4*>(C + (size_t)(b * 512 + n) * T_SEQ + t0) = o; \
        }                                                                      \
    }

// ---------------------------------------------------------------------------
// fp32-input projections (fallback path only).
// ---------------------------------------------------------------------------
__global__ __launch_bounds__(256)
void proj_all(const float* __restrict__ skel, const float* __restrict__ sens,
              const float* __restrict__ Wq1, const float* __restrict__ Wk1,
              const float* __restrict__ Wv1, const float* __restrict__ Wq2,
              const float* __restrict__ Wk2, const float* __restrict__ Wv2,
              unsigned short* __restrict__ Q1, unsigned short* __restrict__ K1,
              unsigned short* __restrict__ Vt1, unsigned short* __restrict__ Q2,
              unsigned short* __restrict__ K2, unsigned short* __restrict__ Vt2,
              int zbase)
{
    const int z = zbase + blockIdx.z;
    const float* A; const float* W; unsigned short* C;
    float alpha = 1.0f; bool trans = false;
    switch (z) {
        case 0:  A = skel; W = Wq1; C = Q1; alpha = SCALE_Q; break;
        case 1:  A = sens; W = Wk1; C = K1; break;
        case 2:  A = sens; W = Wv1; C = Vt1; trans = true; break;
        case 3:  A = sens; W = Wq2; C = Q2; alpha = SCALE_Q; break;
        case 4:  A = skel; W = Wk2; C = K2; break;
        default: A = skel; W = Wv2; C = Vt2; trans = true; break;
    }

    MF_SETUP
    const float* ap = A + (size_t)(m0 + arow) * 512 + acol;
    const float* wp = W + (size_t)(n0 + arow) * 512 + acol;
    float4 av[4], wv[4];
    #pragma unroll
    for (int j = 0; j < 4; ++j) {
        av[j] = *reinterpret_cast<const float4*>(ap + 4 * j);
        wv[j] = *reinterpret_cast<const float4*>(wp + 4 * j);
    }
    for (int it = 0; it < 8; ++it) {
        __syncthreads();
        {
            int4 x;
            x.x = pack2bf(av[0].x, av[0].y); x.y = pack2bf(av[0].z, av[0].w);
            x.z = pack2bf(av[1].x, av[1].y); x.w = pack2bf(av[1].z, av[1].w);
            *reinterpret_cast<int4*>(&Asm[arow][acol]) = x;
            x.x = pack2bf(av[2].x, av[2].y); x.y = pack2bf(av[2].z, av[2].w);
            x.z = pack2bf(av[3].x, av[3].y); x.w = pack2bf(av[3].z, av[3].w);
            *reinterpret_cast<int4*>(&Asm[arow][acol + 8]) = x;
        }
        MF_WRITE_W
        __syncthreads();
        if (it < 7) {
            const float* apn = ap + (it + 1) * 64;
            const float* wpn = wp + (it + 1) * 64;
            #pragma unroll
            for (int j = 0; j < 4; ++j) {
                av[j] = *reinterpret_cast<const float4*>(apn + 4 * j);
                wv[j] = *reinterpret_cast<const float4*>(wpn + 4 * j);
            }
        }
        MF_MMA_LOOP
    }
    MF_CWRITE_PROJ
}

// ---------------------------------------------------------------------------
// Fused all-6-projection GEMM (big path), 128x128 tile, 4 waves (2x2), 4x4
// register blocking (0.5 ds_read/MFMA). A+W double-buffered via
// global_load_lds with 16B-slot XOR swizzle; LDS 64 KB -> 2 blocks/CU.
// Grid 1536, bijective XCD swizzle, nh fastest (A-tile L2 reuse).
// C stored NON-TEMPORALLY (write-once stream; avoids L2 eviction churn).
// ---------------------------------------------------------------------------
__global__ __launch_bounds__(256, 2)
void proj_fused(const unsigned short* __restrict__ skb,
                const unsigned short* __restrict__ snb,
                const unsigned short* __restrict__ wball,
                unsigned short* __restrict__ Q1, unsigned short* __restrict__ K1,
                unsigned short* __restrict__ Vt1, unsigned short* __restrict__ Q2,
                unsigned short* __restrict__ K2, unsigned short* __restrict__ Vt2)
{
    __shared__ __align__(16) char smem[65536];
    short (*Al)[128][64] = reinterpret_cast<short (*)[128][64]>(smem);          // 32 KB
    short (*Wl)[128][64] = reinterpret_cast<short (*)[128][64]>(smem + 32768);  // 32 KB

    // bijective XCD swizzle: nwg=1536, 8 XCDs, q=192
    const int o   = blockIdx.x;
    const int wg  = (o & 7) * 192 + (o >> 3);
    const int z   = wg >> 8;            // 0..5
    const int idx = wg & 255;
    const int nh  = idx & 3;            // n-tile, fastest: A-tile L2 reuse
    const int mt  = idx >> 2;           // 0..63

    const unsigned short* A = (z == 0 || z >= 4) ? skb : snb;
    const unsigned short* W = wball + (size_t)z * W_ELEM;
    unsigned short* C;
    switch (z) {
        case 0: C = Q1;  break;
        case 1: C = K1;  break;
        case 2: C = Vt1; break;
        case 3: C = Q2;  break;
        case 4: C = K2;  break;
        default: C = Vt2; break;
    }
    const bool trans = (z == 2 || z == 5);
    const float alpha = (z == 0 || z == 3) ? SCALE_Q : 1.0f;

    const int tid  = threadIdx.x;
    const int w    = tid >> 6;
    const int wr   = w >> 1;            // wave row (0..1)
    const int wc   = w & 1;             // wave col (0..1)
    const int lane = tid & 63;
    const int nl   = lane & 15;
    const int quad = lane >> 4;
    const int r8   = lane >> 3;
    const int cg   = (lane & 7) ^ r8;   // inverse-swizzled global 16B chunk

    const int m0g = mt * 128;
    const int n0  = nh * 128;

    const unsigned short* Ab = A + (size_t)m0g * 512 + cg * 8;
    const unsigned short* Wb = W + (size_t)n0  * 512 + cg * 8;

    f32x4 acc[4][4] = {};

    auto stage = [&](int it, int buf) {
        const int k0 = it * 64;
        #pragma unroll
        for (int g = 0; g < 4; ++g) {
            const int rr = w * 32 + g * 8;
            gload_lds16(Ab + (size_t)(rr + r8) * 512 + k0, &Al[buf][rr][0]);
            gload_lds16(Wb + (size_t)(rr + r8) * 512 + k0, &Wl[buf][rr][0]);
        }
    };

    stage(0, 0);
    asm volatile("s_waitcnt vmcnt(0)" ::: "memory");
    __syncthreads();

    const int sw = nl & 7;
    for (int it = 0; it < 8; ++it) {
        const int buf = it & 1;
        if (it < 7) stage(it + 1, buf ^ 1);
        #pragma unroll
        for (int kc = 0; kc < 2; ++kc) {
            bf16x8 a[4], bb[4];
            #pragma unroll
            for (int am = 0; am < 4; ++am)
                a[am] = *reinterpret_cast<const bf16x8*>(
                    &Al[buf][wr * 64 + am * 16 + nl][((kc * 4 + quad) ^ sw) * 8]);
            #pragma unroll
            for (int bn = 0; bn < 4; ++bn)
                bb[bn] = *reinterpret_cast<const bf16x8*>(
                    &Wl[buf][wc * 64 + bn * 16 + nl][((kc * 4 + quad) ^ sw) * 8]);
            #pragma unroll
            for (int am = 0; am < 4; ++am)
                #pragma unroll
                for (int bn = 0; bn < 4; ++bn)
                    acc[am][bn] = __builtin_amdgcn_mfma_f32_16x16x32_bf16(
                        a[am], bb[bn], acc[am][bn], 0, 0, 0);
        }
        asm volatile("s_waitcnt vmcnt(0)" ::: "memory");
        __syncthreads();
    }

    // ---- staged coalesced epilogue, NON-TEMPORAL C stores ----
    if (!trans) {
        short (*Cl)[136] = reinterpret_cast<short (*)[136]>(smem);  // 34.8 KB
        #pragma unroll
        for (int am = 0; am < 4; ++am)
            #pragma unroll
            for (int bn = 0; bn < 4; ++bn)
                #pragma unroll
                for (int r = 0; r < 4; ++r)
                    Cl[wr * 64 + am * 16 + quad * 4 + r][wc * 64 + bn * 16 + nl] =
                        (short)f2b(acc[am][bn][r] * alpha);
        __syncthreads();
        const int lr = tid >> 1;            // 0..127 (m row)
        const int ch = (tid & 1) * 64;      // short col half
        unsigned short* cp = C + (size_t)(m0g + lr) * 512 + n0 + ch;
        #pragma unroll
        for (int j = 0; j < 8; ++j)
            nt_store_i4(cp + j * 8, &Cl[lr][ch + j * 8]);
    } else {
        short (*Tl)[136] = reinterpret_cast<short (*)[136]>(smem);  // 34.8 KB
        #pragma unroll
        for (int am = 0; am < 4; ++am)
            #pragma unroll
            for (int bn = 0; bn < 4; ++bn) {
                int* dst = reinterpret_cast<int*>(
                    &Tl[wc * 64 + bn * 16 + nl][wr * 64 + am * 16 + quad * 4]);
                dst[0] = pack2bf(acc[am][bn][0], acc[am][bn][1]);
                dst[1] = pack2bf(acc[am][bn][2], acc[am][bn][3]);
            }
        __syncthreads();
        const int bq = m0g >> 11;
        const int t0 = m0g & 2047;
        const int nr = tid >> 1;            // 0..127 (n row)
        const int tc = (tid & 1) * 64;      // t chunk half
        unsigned short* vp = C + (size_t)(bq * 512 + n0 + nr) * T_SEQ + t0 + tc;
        #pragma unroll
        for (int j = 0; j < 8; ++j)
            nt_store_i4(vp + j * 8, &Tl[nr][tc + j * 8]);
    }
}

// ---------------------------------------------------------------------------
// Fused output projections (big path), same 128x128 / 4x4-blocked structure.
// A = AO bf16 via gload_lds; W fp32 reg-staged -> swizzled bf16 LDS; fp32 C
// staged through LDS and stored NON-TEMPORALLY. 2 blocks/CU.
// Grid 512 = 2 z x 64 mt x 4 nh, bijective XCD swizzle (q=64).
// ---------------------------------------------------------------------------
__global__ __launch_bounds__(256, 2)
void out_fused(const unsigned short* __restrict__ AO1, const float* __restrict__ Wo1,
               float* __restrict__ C1,
               const unsigned short* __restrict__ AO2, const float* __restrict__ Wo2,
               float* __restrict__ C2)
{
    __shared__ __align__(16) char smem[67584];
    short (*Al)[128][64] = reinterpret_cast<short (*)[128][64]>(smem);          // 32 KB
    short (*Wl)[128][64] = reinterpret_cast<short (*)[128][64]>(smem + 32768);  // 32 KB

    const int o   = blockIdx.x;              // 512
    const int wg  = (o & 7) * 64 + (o >> 3); // bijective, 512 % 8 == 0
    const int z   = wg >> 8;
    const int idx = wg & 255;
    const int nh  = idx & 3;
    const int mt  = idx >> 2;

    const unsigned short* A = z ? AO2 : AO1;
    const float* W = z ? Wo2 : Wo1;
    float* C = z ? C2 : C1;

    const int tid  = threadIdx.x;
    const int w    = tid >> 6;
    const int wr   = w >> 1;
    const int wc   = w & 1;
    const int lane = tid & 63;
    const int nl   = lane & 15;
    const int quad = lane >> 4;
    const int r8   = lane >> 3;
    const int cg   = (lane & 7) ^ r8;

    const int m0g = mt * 128;
    const int n0  = nh * 128;

    const unsigned short* Ab = A + (size_t)m0g * 512 + cg * 8;

    // W staging: thread covers row tid>>1 (128 rows, 2 threads/row), 32
    // contiguous floats at k0 + (tid&1)*32. Swizzled bf16 store: logical
    // slot (tid&1)*4 + (j>>1), offset (j&1)*4 shorts, phys = slot^(row&7).
    const int rw_ = tid >> 1;
    const int ch_ = (tid & 1) * 32;
    const int key = rw_ & 7;

    f32x4 acc[4][4] = {};
    float4 wreg[8];

    auto stageA = [&](int it, int buf) {
        const int k0 = it * 64;
        #pragma unroll
        for (int g = 0; g < 4; ++g) {
            const int rr = w * 32 + g * 8;
            gload_lds16(Ab + (size_t)(rr + r8) * 512 + k0, &Al[buf][rr][0]);
        }
    };
    auto wload = [&](int it) {
        const float* wp = W + (size_t)(n0 + rw_) * 512 + it * 64 + ch_;
        #pragma unroll
        for (int j = 0; j < 8; ++j)
            wreg[j] = *reinterpret_cast<const float4*>(wp + 4 * j);
    };
    auto wstore = [&](int buf) {
        #pragma unroll
        for (int j = 0; j < 8; ++j) {
            int2 pk;
            pk.x = pack2bf(wreg[j].x, wreg[j].y);
            pk.y = pack2bf(wreg[j].z, wreg[j].w);
            const int slot = ((tid & 1) * 4 + (j >> 1)) ^ key;
            *reinterpret_cast<int2*>(
                &Wl[buf][rw_][slot * 8 + (j & 1) * 4]) = pk;
        }
    };

    // prologue
    wload(0);
    stageA(0, 0);
    asm volatile("s_waitcnt vmcnt(0)" ::: "memory");
    wstore(0);
    __syncthreads();

    const int sw = nl & 7;
    for (int it = 0; it < 8; ++it) {
        const int buf = it & 1;
        if (it < 7) { stageA(it + 1, buf ^ 1); wload(it + 1); }
        #pragma unroll
        for (int kc = 0; kc < 2; ++kc) {
            bf16x8 a[4], bb[4];
            #pragma unroll
            for (int am = 0; am < 4; ++am)
                a[am] = *reinterpret_cast<const bf16x8*>(
                    &Al[buf][wr * 64 + am * 16 + nl][((kc * 4 + quad) ^ sw) * 8]);
            #pragma unroll
            for (int bn = 0; bn < 4; ++bn)
                bb[bn] = *reinterpret_cast<const bf16x8*>(
                    &Wl[buf][wc * 64 + bn * 16 + nl][((kc * 4 + quad) ^ sw) * 8]);
            #pragma unroll
            for (int am = 0; am < 4; ++am)
                #pragma unroll
                for (int bn = 0; bn < 4; ++bn)
                    acc[am][bn] = __builtin_amdgcn_mfma_f32_16x16x32_bf16(
                        a[am], bb[bn], acc[am][bn], 0, 0, 0);
        }
        asm volatile("s_waitcnt vmcnt(0)" ::: "memory");
        if (it < 7) wstore(buf ^ 1);
        __syncthreads();
    }

    // ---- fp32 epilogue staged through LDS, NON-TEMPORAL 256B/thread ----
    float (*Cl)[132] = reinterpret_cast<float (*)[132]>(smem);   // 67.6 KB
    #pragma unroll
    for (int am = 0; am < 4; ++am)
        #pragma unroll
        for (int bn = 0; bn < 4; ++bn)
            #pragma unroll
            for (int r = 0; r < 4; ++r)
                Cl[wr * 64 + am * 16 + quad * 4 + r][wc * 64 + bn * 16 + nl] =
                    acc[am][bn][r];
    __syncthreads();
    const int lr = tid >> 1;            // 0..127
    const int fc = (tid & 1) * 64;      // float col half
    float* cp = C + (size_t)(m0g + lr) * 512 + n0 + fc;
    #pragma unroll
    for (int j = 0; j < 16; ++j)
        nt_store_f4(cp + j * 4, &Cl[lr][fc + j * 4]);
}

// ---------------------------------------------------------------------------
// Fallback output projection (small-ws path only).
// ---------------------------------------------------------------------------
__global__ __launch_bounds__(256)
void out_proj(const unsigned short* __restrict__ AO1, const float* __restrict__ Wo1,
              float* __restrict__ C1,
              const unsigned short* __restrict__ AO2, const float* __restrict__ Wo2,
              float* __restrict__ C2, int zbase)
{
    const int z = zbase + blockIdx.z;
    const unsigned short* A = z ? AO2 : AO1;
    const float* W = z ? Wo2 : Wo1;
    float* C = z ? C2 : C1;

    MF_SETUP
    const unsigned short* ap = A + (size_t)(m0 + arow) * 512 + acol;
    const float* wp = W + (size_t)(n0 + arow) * 512 + acol;
    int4 ai[2];
    float4 wv[4];
    ai[0] = *reinterpret_cast<const int4*>(ap);
    ai[1] = *reinterpret_cast<const int4*>(ap + 8);
    #pragma unroll
    for (int j = 0; j < 4; ++j)
        wv[j] = *reinterpret_cast<const float4*>(wp + 4 * j);
    for (int it = 0; it < 8; ++it) {
        __syncthreads();
        *reinterpret_cast<int4*>(&Asm[arow][acol])     = ai[0];
        *reinterpret_cast<int4*>(&Asm[arow][acol + 8]) = ai[1];
        MF_WRITE_W
        __syncthreads();
        if (it < 7) {
            const unsigned short* apn = ap + (it + 1) * 64;
            const float* wpn = wp + (it + 1) * 64;
            ai[0] = *reinterpret_cast<const int4*>(apn);
            ai[1] = *reinterpret_cast<const int4*>(apn + 8);
            #pragma unroll
            for (int j = 0; j < 4; ++j)
                wv[j] = *reinterpret_cast<const float4*>(wpn + 4 * j);
        }
        MF_MMA_LOOP
    }
    #pragma unroll
    for (int c = 0; c < 4; ++c)
        #pragma unroll
        for (int r = 0; r < 4; ++r)
            C[(size_t)(m0 + w4 * 16 + quad * 4 + r) * 512 + n0 + c * 16 + nl] =
                acc[c][r];
}

// ---------------------------------------------------------------------------
// MFMA flash attention, ONE direction per dispatch (launched twice). Block =
// 8 waves / 512 threads = one (b,h,128-row q-tile); wave owns 16 q rows.
// K/V LDS tiles shared by all 8 waves; LDS 48 KB. K/V staged via
// global_load_lds (double-buffered, swizzled); FIXED-MAX softmax
// (log2-domain, m=0 exact-equivalent); mask bias rides the QK MFMA C-input;
// l-reduce once at epilogue; s_setprio(1) wraps PV cluster. AO aliases Q
// (block-local RAW only).
// ---------------------------------------------------------------------------
__global__ __launch_bounds__(512)
void attn_mfma(const unsigned short* Q, const unsigned short* __restrict__ K,
               const unsigned short* __restrict__ Vt, const float* __restrict__ biasD,
               unsigned short* AO)
{
    __shared__ short Kl[2][64][64];   // [buf][kv_row][d] (swizzled 16B slots)
    __shared__ short Vl[2][64][64];   // [buf][d_row][kv] (swizzled 16B slots)
    __shared__ short Pl[8][16][64];   // pitch 64 + slot-XOR; total LDS = 48 KB

    const int tid  = threadIdx.x;
    const int w    = tid >> 6;              // 0..7
    const int lane = tid & 63;
    const int nl   = lane & 15;
    const int quad = lane >> 4;
    const int qt = blockIdx.x;              // 0..15 (128-row q-tiles)
    const int bh = blockIdx.y & 31;         // 0..31
    const int b = bh >> 3, h = bh & 7;
    const size_t tb = (size_t)b * (T_SEQ * 512);
    const float* biasB = biasD + b * T_SEQ;

    const int r8 = lane >> 3;
    const int cg = (lane & 7) ^ r8;
    const int sr = w * 8;                   // this wave's staging row base

    // Q B-frags (n=lane&15 => q row, k=quad*8+j)
    const unsigned short* qp = Q + tb + (size_t)(qt * 128 + w * 16 + nl) * 512 + h * 64 + quad * 8;
    const bf16x8 qb0 = ldg8(qp);
    const bf16x8 qb1 = ldg8(qp + 32);

    float l_run = 0.0f;   // lane-local partial (this lane's kv slots only)
    f32x4 o[4] = {};   // O^T: o[sd] holds d = sd*16+quad*4+r (row), q = nl (col)

    // prologue: stage tile 0 into buffer 0
    gload_lds16(K  + tb + (size_t)(sr + r8) * 512 + h * 64 + cg * 8, &Kl[0][sr][0]);
    gload_lds16(Vt + (size_t)(b * 512 + h * 64 + sr + r8) * T_SEQ + cg * 8, &Vl[0][sr][0]);
    asm volatile("s_waitcnt vmcnt(0)" ::: "memory");
    __syncthreads();

    const int swz = nl & 7;

    for (int kt = 0; kt < 32; ++kt) {
        const int cur = kt & 1;
        short (*Kb)[64] = Kl[cur];
        short (*Vb)[64] = Vl[cur];

        // issue next tile's DMA (lands before next iteration's barrier)
        if (kt < 31) {
            short (*Kn)[64] = Kl[cur ^ 1];
            short (*Vn)[64] = Vl[cur ^ 1];
            gload_lds16(K  + tb + (size_t)((kt + 1) * 64 + sr + r8) * 512 + h * 64 + cg * 8, &Kn[sr][0]);
            gload_lds16(Vt + (size_t)(b * 512 + h * 64 + sr + r8) * T_SEQ + (size_t)(kt + 1) * 64 + cg * 8, &Vn[sr][0]);
        }

        // scores S^T[kv][q] (log2 domain); mask bias enters as MFMA C-input
        float p[4][4];
        #pragma unroll
        for (int s = 0; s < 4; ++s) {
            const bf16x8 k0 = *reinterpret_cast<const bf16x8*>(&Kb[s * 16 + nl][(quad ^ swz) * 8]);
            const bf16x8 k1 = *reinterpret_cast<const bf16x8*>(&Kb[s * 16 + nl][((4 + quad) ^ swz) * 8]);
            const float4 bb = *reinterpret_cast<const float4*>(
                &biasB[kt * 64 + s * 16 + quad * 4]);
            f32x4 z = {bb.x, bb.y, bb.z, bb.w};
            z = __builtin_amdgcn_mfma_f32_16x16x32_bf16(k0, qb0, z, 0, 0, 0);
            z = __builtin_amdgcn_mfma_f32_16x16x32_bf16(k1, qb1, z, 0, 0, 0);
            p[s][0] = fexp2(z[0]);
            p[s][1] = fexp2(z[1]);
            p[s][2] = fexp2(z[2]);
            p[s][3] = fexp2(z[3]);
            l_run += p[s][0] + p[s][1] + p[s][2] + p[s][3];
        }

        // P -> LDS [q][kv], pitch 64 with 16B-slot XOR (key = nl&7).
        #pragma unroll
        for (int s = 0; s < 4; ++s) {
            int2 pk;
            pk.x = pack2bf(p[s][0], p[s][1]);
            pk.y = pack2bf(p[s][2], p[s][3]);
            const int slot = (2 * s + (quad >> 1)) ^ swz;
            *reinterpret_cast<int2*>(&Pl[w][nl][slot * 8 + (quad & 1) * 4]) = pk;
        }

        // O^T += V^T · P^T (pa read back with the same slot-XOR)
        const bf16x8 pa0 = *reinterpret_cast<const bf16x8*>(&Pl[w][nl][(quad ^ swz) * 8]);
        const bf16x8 pa1 = *reinterpret_cast<const bf16x8*>(&Pl[w][nl][((4 + quad) ^ swz) * 8]);
        __builtin_amdgcn_s_setprio(1);
        #pragma unroll
        for (int sd = 0; sd < 4; ++sd) {
            const bf16x8 v0 = *reinterpret_cast<const bf16x8*>(&Vb[sd * 16 + nl][(quad ^ swz) * 8]);
            const bf16x8 v1 = *reinterpret_cast<const bf16x8*>(&Vb[sd * 16 + nl][((4 + quad) ^ swz) * 8]);
            o[sd] = __builtin_amdgcn_mfma_f32_16x16x32_bf16(v0, pa0, o[sd], 0, 0, 0);
            o[sd] = __builtin_amdgcn_mfma_f32_16x16x32_bf16(v1, pa1, o[sd], 0, 0, 0);
        }
        __builtin_amdgcn_s_setprio(0);

        // drain this iteration's DMA, release buffers
        asm volatile("s_waitcnt vmcnt(0)" ::: "memory");
        __syncthreads();
    }

    // epilogue: reduce l across the 4 kv-quadrant lanes ONCE, then store
    l_run += __shfl_xor(l_run, 16);
    l_run += __shfl_xor(l_run, 32);
    const float inv = 1.0f / l_run;
    unsigned short* ob = AO + tb + (size_t)(qt * 128 + w * 16 + nl) * 512 + h * 64 + quad * 4;
    #pragma unroll
    for (int sd = 0; sd < 4; ++sd) {
        ushort4 o4;
        o4.x = f2b(o[sd][0] * inv);
        o4.y = f2b(o[sd][1] * inv);
        o4.z = f2b(o[sd][2] * inv);
        o4.w = f2b(o[sd][3] * inv);
        *reinterpret_cast<ushort4*>(ob + sd * 16) = o4;
    }
}

extern "C" void kernel_launch(void* const* d_in, const int* in_sizes, int n_in,
                              void* d_out, int out_size, void* d_ws, size_t ws_size,
                              hipStream_t stream) {
    const float* skel = (const float*)d_in[0];
    const float* sens = (const float*)d_in[1];
    const int* mask_skel = (const int*)d_in[2];
    const int* mask_sens = (const int*)d_in[3];
    const float* Wq_s2e = (const float*)d_in[4];
    const float* Wk_e   = (const float*)d_in[5];
    const float* Wv_e   = (const float*)d_in[6];
    const float* Wq_e2s = (const float*)d_in[7];
    const float* Wk_s   = (const float*)d_in[8];
    const float* Wv_s   = (const float*)d_in[9];
    const float* Wo_s   = (const float*)d_in[10];
    const float* Wo_e   = (const float*)d_in[11];
    float* out = (float*)d_out;   // fp32: [e2s (4M)][s2e (4M)]

    unsigned short* Q1 = (unsigned short*)d_ws;    // dir0 Q / AO (aliased)
    unsigned short* K1 = Q1 + N_TOK;
    unsigned short* V1 = K1 + N_TOK;               // Vt

    const bool big = ws_size >= (size_t)6 * N_TOK * sizeof(unsigned short);

    if (big) {
        unsigned short* Q2 = V1 + N_TOK;
        unsigned short* K2 = Q2 + N_TOK;
        unsigned short* V2 = K2 + N_TOK;
        // bf16+bias scratch lives in d_out (dead until out_fused, stream order)
        unsigned short* SC  = (unsigned short*)d_out;
        unsigned short* skb = SC;
        unsigned short* snb = SC + N_TOK;
        unsigned short* wb  = SC + 2 * (size_t)N_TOK;
        float* biasS = (float*)(SC + 2 * (size_t)N_TOK + 6 * W_ELEM);
        float* bias0 = biasS;                 // dir0 <- mask_sens
        float* bias1 = biasS + 4 * T_SEQ;     // dir1 <- mask_skel
        prep_bias<<<dim3(8), 256, 0, stream>>>(mask_sens, mask_skel, biasS);
        to_bf16<<<dim3(4864), 256, 0, stream>>>(
            skel, sens, Wq_s2e, Wk_e, Wv_e, Wq_e2s, Wk_s, Wv_s, SC);
        // dir0 = s2e (out slot 1), dir1 = e2s (out slot 0)
        proj_fused<<<dim3(1536), 256, 0, stream>>>(
            skb, snb, wb, Q1, K1, V1, Q2, K2, V2);
        attn_mfma<<<dim3(16, 32), 512, 0, stream>>>(Q1, K1, V1, bias0, Q1);
        attn_mfma<<<dim3(16, 32), 512, 0, stream>>>(Q2, K2, V2, bias1, Q2);
        out_fused<<<dim3(512), 256, 0, stream>>>(
            Q1, Wo_e, out + N_TOK, Q2, Wo_s, out);
    } else {
        // sequential fallback: reuse the 3-buffer workspace per direction.
        // bias scratch in the e2s half of out (overwritten by the LAST
        // out_proj, after its final use).
        float* bias0 = out;                   // dir0 <- mask_sens
        float* bias1 = out + 8192;            // dir1 <- mask_skel
        prep_bias<<<dim3(8), 256, 0, stream>>>(mask_sens, mask_skel, bias0);
        proj_all<<<dim3(8, 128, 3), 256, 0, stream>>>(
            skel, sens, Wq_s2e, Wk_e, Wv_e, Wq_e2s, Wk_s, Wv_s,
            Q1, K1, V1, Q1, K1, V1, 0);
        attn_mfma<<<dim3(16, 32), 512, 0, stream>>>(Q1, K1, V1, bias0, Q1);
        out_proj<<<dim3(8, 128, 1), 256, 0, stream>>>(
            Q1, Wo_e, out + N_TOK, Q1, Wo_s, out, 0);
        proj_all<<<dim3(8, 128, 3), 256, 0, stream>>>(
            skel, sens, Wq_s2e, Wk_e, Wv_e, Wq_e2s, Wk_s, Wv_s,
            Q1, K1, V1, Q1, K1, V1, 3);
        attn_mfma<<<dim3(16, 32), 512, 0, stream>>>(Q1, K1, V1, bias1, Q1);
        out_proj<<<dim3(8, 128, 1), 256, 0, stream>>>(
            Q1, Wo_s, out, Q1, Wo_s, out, 1);
    }
}

// Round 11
// 283.891 us; speedup vs baseline: 1.5249x; 1.5249x over previous
//
#include <hip/hip_runtime.h>
#include <hip/hip_bf16.h>

// Problem constants: B=4, T=2048, D=512, H=8, DK=64
#define T_SEQ 2048
#define N_TOK 4194304   // 4 * 2048 * 512 elements per [B,T,D] tensor
#define W_ELEM 262144   // 512*512

// Inputs: FLOAT32. Output: FLOAT32, (e2s, s2e) concat.
// ws (fused path, 48 MB): Q1,K1 [B,T,512] bf16; Vt1 [B,512,T] bf16; Q2,K2,Vt2.
// AO aliases Q per direction. Fallback (<48 MB ws): 24 MB, sequential.
// Big path: d_out doubles as scratch (skel,sens bf16; 6 proj W bf16; bias
// floats) until out_fused runs (strict stream order).

typedef float f32x4  __attribute__((ext_vector_type(4)));
typedef short bf16x8 __attribute__((ext_vector_type(8)));

// 1.5/sqrt(64) * log2(e): attention logits are produced in log2 domain so
// softmax uses bare v_exp_f32 (exp2) with no per-element multiply.
#define SCALE_Q 0.27050532f

__device__ __forceinline__ unsigned short f2b(float f) {
    __hip_bfloat16 h = __float2bfloat16(f);
    return *reinterpret_cast<unsigned short*>(&h);
}

__device__ __forceinline__ int pack2bf(float lo, float hi) {
    return ((int)f2b(hi) << 16) | (int)f2b(lo);
}

__device__ __forceinline__ bf16x8 ldg8(const unsigned short* p) {
    union { int4 i; bf16x8 b; } u;
    u.i = *reinterpret_cast<const int4*>(p);
    return u.b;
}

__device__ __forceinline__ float fexp2(float x) {
#if __has_builtin(__builtin_amdgcn_exp2f)
    return __builtin_amdgcn_exp2f(x);
#else
    return exp2f(x);
#endif
}

// async global->LDS DMA, 16B per lane; LDS dest = wave-uniform base + lane*16
typedef unsigned int u32_g __attribute__((address_space(1)));
typedef unsigned int u32_l __attribute__((address_space(3)));
__device__ __forceinline__ void gload_lds16(const void* g, void* l) {
    __builtin_amdgcn_global_load_lds((const u32_g*)g, (u32_l*)l, 16, 0, 0);
}

// raw barrier (no compiler-inserted vmcnt(0) drain) with scheduling fences
__device__ __forceinline__ void raw_barrier() {
    __builtin_amdgcn_sched_barrier(0);
    __builtin_amdgcn_s_barrier();
    __builtin_amdgcn_sched_barrier(0);
}

// ---------------------------------------------------------------------------
// mask -> additive float bias precompute: dst = [2][B][T_SEQ] floats (64 KB).
// dir0 <- mask_sens, dir1 <- mask_skel.
// ---------------------------------------------------------------------------
__global__ __launch_bounds__(256)
void prep_bias(const int* __restrict__ ms, const int* __restrict__ mk,
               float* __restrict__ dst)
{
    const int i = (blockIdx.x * 256 + threadIdx.x) * 8;   // 16384 total
    const int* m = (i >> 13) ? mk : ms;
    const int rem = i & 8191;
    const int4 a = *reinterpret_cast<const int4*>(&m[rem]);
    const int4 b = *reinterpret_cast<const int4*>(&m[rem + 4]);
    float4 f0, f1;
    f0.x = a.x ? 0.0f : -3e38f; f0.y = a.y ? 0.0f : -3e38f;
    f0.z = a.z ? 0.0f : -3e38f; f0.w = a.w ? 0.0f : -3e38f;
    f1.x = b.x ? 0.0f : -3e38f; f1.y = b.y ? 0.0f : -3e38f;
    f1.z = b.z ? 0.0f : -3e38f; f1.w = b.w ? 0.0f : -3e38f;
    *reinterpret_cast<float4*>(&dst[i])     = f0;
    *reinterpret_cast<float4*>(&dst[i + 4]) = f1;
}

// ---------------------------------------------------------------------------
// fp32 -> bf16 pre-conversion, exact 1D grid (4864 blocks):
// [0,2048) skel, [2048,4096) sens, then 6 x 128 blocks for proj weights.
// dst layout: [skel 4M][sens 4M][W0..W5 x 256K] shorts (19 MB).
// ---------------------------------------------------------------------------
__global__ __launch_bounds__(256)
void to_bf16(const float* __restrict__ s0, const float* __restrict__ s1,
             const float* __restrict__ w0, const float* __restrict__ w1,
             const float* __restrict__ w2, const float* __restrict__ w3,
             const float* __restrict__ w4, const float* __restrict__ w5,
             unsigned short* __restrict__ dst)
{
    const int bid = blockIdx.x;
    int y, x;
    if (bid < 4096) { y = bid >> 11; x = bid & 2047; }
    else { const int t = bid - 4096; y = 2 + (t >> 7); x = t & 127; }
    const float* src;
    size_t off;
    switch (y) {
        case 0: src = s0; off = 0;      break;
        case 1: src = s1; off = N_TOK;  break;
        case 2: src = w0; off = 2 * (size_t)N_TOK;              break;
        case 3: src = w1; off = 2 * (size_t)N_TOK + 1 * W_ELEM; break;
        case 4: src = w2; off = 2 * (size_t)N_TOK + 2 * W_ELEM; break;
        case 5: src = w3; off = 2 * (size_t)N_TOK + 3 * W_ELEM; break;
        case 6: src = w4; off = 2 * (size_t)N_TOK + 4 * W_ELEM; break;
        default: src = w5; off = 2 * (size_t)N_TOK + 5 * W_ELEM; break;
    }
    const int idx = (x * 256 + threadIdx.x) * 8;
    const float4 a = *reinterpret_cast<const float4*>(src + idx);
    const float4 b = *reinterpret_cast<const float4*>(src + idx + 4);
    int4 o;
    o.x = pack2bf(a.x, a.y); o.y = pack2bf(a.z, a.w);
    o.z = pack2bf(b.x, b.y); o.w = pack2bf(b.z, b.w);
    *reinterpret_cast<int4*>(dst + off + idx) = o;
}

// ---------------------------------------------------------------------------
// Shared MFMA-GEMM tile machinery (fallback proj + fallback out_proj).
// ---------------------------------------------------------------------------
#define MF_SETUP                                                               \
    __shared__ short Asm[64][72];                                              \
    __shared__ short Wsm[64][72];                                              \
    const int tid  = threadIdx.x;                                              \
    const int lane = tid & 63;                                                 \
    const int w4   = tid >> 6;                                                 \
    const int nl   = lane & 15;                                                \
    const int quad = lane >> 4;                                                \
    const int n0 = blockIdx.x * 64;                                            \
    const int m0 = blockIdx.y * 64;                                            \
    const int arow = tid >> 2;                                                 \
    const int acol = (tid & 3) * 16;                                           \
    f32x4 acc[4] = {};

#define MF_WRITE_W                                                             \
    {                                                                          \
        int4 x;                                                                \
        x.x = pack2bf(wv[0].x, wv[0].y); x.y = pack2bf(wv[0].z, wv[0].w);      \
        x.z = pack2bf(wv[1].x, wv[1].y); x.w = pack2bf(wv[1].z, wv[1].w);      \
        *reinterpret_cast<int4*>(&Wsm[arow][acol]) = x;                        \
        x.x = pack2bf(wv[2].x, wv[2].y); x.y = pack2bf(wv[2].z, wv[2].w);      \
        x.z = pack2bf(wv[3].x, wv[3].y); x.w = pack2bf(wv[3].z, wv[3].w);      \
        *reinterpret_cast<int4*>(&Wsm[arow][acol + 8]) = x;                    \
    }

#define MF_MMA_LOOP                                                            \
    _Pragma("unroll")                                                          \
    for (int kc = 0; kc < 2; ++kc) {                                           \
        const bf16x8 a = *reinterpret_cast<const bf16x8*>(                     \
            &Asm[w4 * 16 + nl][kc * 32 + quad * 8]);                           \
        _Pragma("unroll")                                                      \
        for (int c = 0; c < 4; ++c) {                                          \
            const bf16x8 bf = *reinterpret_cast<const bf16x8*>(                \
                &Wsm[c * 16 + nl][kc * 32 + quad * 8]);                        \
            acc[c] = __builtin_amdgcn_mfma_f32_16x16x32_bf16(a, bf, acc[c],    \
                                                             0, 0, 0);         \
        }                                                                      \
    }

#define MF_CWRITE_PROJ                                                         \
    if (!trans) {                                                              \
        _Pragma("unroll")                                                      \
        for (int c = 0; c < 4; ++c)                                            \
            _Pragma("unroll")                                                  \
            for (int r = 0; r < 4; ++r)                                        \
                C[(size_t)(m0 + w4 * 16 + quad * 4 + r) * 512 + n0 + c * 16 + nl] = \
                    f2b(acc[c][r] * alpha);                                    \
    } else {                                                                   \
        const int b  = m0 >> 11;                                               \
        const int t0 = (m0 & 2047) + w4 * 16 + quad * 4;                       \
        _Pragma("unroll")                                                      \
        for (int c = 0; c < 4; ++c) {                                          \
            const int n = n0 + c * 16 + nl;                                    \
            ushort4 o;                                                         \
            o.x = f2b(acc[c][0]);                                              \
            o.y = f2b(acc[c][1]);                                              \
            o.z = f2b(acc[c][2]);                                              \
            o.w = f2b(acc[c][3]);                                              \
            *reinterpret_cast<ushort4*>(C + (size_t)(b * 512 + n) * T_SEQ + t0) = o; \
        }                                                                      \
    }

// ---------------------------------------------------------------------------
// fp32-input projections (fallback path only).
// ---------------------------------------------------------------------------
__global__ __launch_bounds__(256)
void proj_all(const float* __restrict__ skel, const float* __restrict__ sens,
              const float* __restrict__ Wq1, const float* __restrict__ Wk1,
              const float* __restrict__ Wv1, const float* __restrict__ Wq2,
              const float* __restrict__ Wk2, const float* __restrict__ Wv2,
              unsigned short* __restrict__ Q1, unsigned short* __restrict__ K1,
              unsigned short* __restrict__ Vt1, unsigned short* __restrict__ Q2,
              unsigned short* __restrict__ K2, unsigned short* __restrict__ Vt2,
              int zbase)
{
    const int z = zbase + blockIdx.z;
    const float* A; const float* W; unsigned short* C;
    float alpha = 1.0f; bool trans = false;
    switch (z) {
        case 0:  A = skel; W = Wq1; C = Q1; alpha = SCALE_Q; break;
        case 1:  A = sens; W = Wk1; C = K1; break;
        case 2:  A = sens; W = Wv1; C = Vt1; trans = true; break;
        case 3:  A = sens; W = Wq2; C = Q2; alpha = SCALE_Q; break;
        case 4:  A = skel; W = Wk2; C = K2; break;
        default: A = skel; W = Wv2; C = Vt2; trans = true; break;
    }

    MF_SETUP
    const float* ap = A + (size_t)(m0 + arow) * 512 + acol;
    const float* wp = W + (size_t)(n0 + arow) * 512 + acol;
    float4 av[4], wv[4];
    #pragma unroll
    for (int j = 0; j < 4; ++j) {
        av[j] = *reinterpret_cast<const float4*>(ap + 4 * j);
        wv[j] = *reinterpret_cast<const float4*>(wp + 4 * j);
    }
    for (int it = 0; it < 8; ++it) {
        __syncthreads();
        {
            int4 x;
            x.x = pack2bf(av[0].x, av[0].y); x.y = pack2bf(av[0].z, av[0].w);
            x.z = pack2bf(av[1].x, av[1].y); x.w = pack2bf(av[1].z, av[1].w);
            *reinterpret_cast<int4*>(&Asm[arow][acol]) = x;
            x.x = pack2bf(av[2].x, av[2].y); x.y = pack2bf(av[2].z, av[2].w);
            x.z = pack2bf(av[3].x, av[3].y); x.w = pack2bf(av[3].z, av[3].w);
            *reinterpret_cast<int4*>(&Asm[arow][acol + 8]) = x;
        }
        MF_WRITE_W
        __syncthreads();
        if (it < 7) {
            const float* apn = ap + (it + 1) * 64;
            const float* wpn = wp + (it + 1) * 64;
            #pragma unroll
            for (int j = 0; j < 4; ++j) {
                av[j] = *reinterpret_cast<const float4*>(apn + 4 * j);
                wv[j] = *reinterpret_cast<const float4*>(wpn + 4 * j);
            }
        }
        MF_MMA_LOOP
    }
    MF_CWRITE_PROJ
}

// ---------------------------------------------------------------------------
// Fused all-6-projection GEMM (big path), 128x128 tile, 4 waves (2x2), 4x4
// register blocking. NEW: BK=32 with a 3-buffer counted-vmcnt pipeline —
// each k-step issues 4 gload_lds/thread for step i+2, computes step i, then
// waits vmcnt(4) (stage i+1 complete, i+2 still in flight) at a RAW s_barrier
// (no compiler vmcnt(0) drain). Loads are never drained to zero in the main
// loop (T3+T4). LDS 48 KB -> 3 blocks/CU (was 2). Plain C stores (keep C in
// L2/L3 for attn; nt stores measured 4x write-through amplification in R10).
// Swizzle (4 slots/row): read slot = quad ^ ((nl>>1)&3); global source
// pre-swizzled cg = (l&3)^((l>>3)&3) -> 8 distinct banks (2-way, free).
// ---------------------------------------------------------------------------
__global__ __launch_bounds__(256, 3)
void proj_fused(const unsigned short* __restrict__ skb,
                const unsigned short* __restrict__ snb,
                const unsigned short* __restrict__ wball,
                unsigned short* __restrict__ Q1, unsigned short* __restrict__ K1,
                unsigned short* __restrict__ Vt1, unsigned short* __restrict__ Q2,
                unsigned short* __restrict__ K2, unsigned short* __restrict__ Vt2)
{
    __shared__ __align__(16) char smem[49152];
    short (*Al)[128][32] = reinterpret_cast<short (*)[128][32]>(smem);           // 24 KB
    short (*Wl)[128][32] = reinterpret_cast<short (*)[128][32]>(smem + 24576);   // 24 KB

    // bijective XCD swizzle: nwg=1536, 8 XCDs, q=192
    const int o   = blockIdx.x;
    const int wg  = (o & 7) * 192 + (o >> 3);
    const int z   = wg >> 8;            // 0..5
    const int idx = wg & 255;
    const int nh  = idx & 3;            // n-tile, fastest: A-tile L2 reuse
    const int mt  = idx >> 2;           // 0..63

    const unsigned short* A = (z == 0 || z >= 4) ? skb : snb;
    const unsigned short* W = wball + (size_t)z * W_ELEM;
    unsigned short* C;
    switch (z) {
        case 0: C = Q1;  break;
        case 1: C = K1;  break;
        case 2: C = Vt1; break;
        case 3: C = Q2;  break;
        case 4: C = K2;  break;
        default: C = Vt2; break;
    }
    const bool trans = (z == 2 || z == 5);
    const float alpha = (z == 0 || z == 3) ? SCALE_Q : 1.0f;

    const int tid  = threadIdx.x;
    const int w    = tid >> 6;
    const int wr   = w >> 1;            // wave row (0..1)
    const int wc   = w & 1;             // wave col (0..1)
    const int lane = tid & 63;
    const int nl   = lane & 15;
    const int quad = lane >> 4;
    const int rof  = lane >> 2;                      // row offset in 16-row group
    const int cg   = (lane & 3) ^ ((lane >> 3) & 3); // inverse-swizzled chunk

    const int m0g = mt * 128;
    const int n0  = nh * 128;

    // per-thread source bases: two 16-row groups for A and for W
    const unsigned short* srcA0 = A + (size_t)(m0g + w * 32 + rof) * 512 + cg * 8;
    const unsigned short* srcA1 = srcA0 + (size_t)16 * 512;
    const unsigned short* srcW0 = W + (size_t)(n0 + w * 32 + rof) * 512 + cg * 8;
    const unsigned short* srcW1 = srcW0 + (size_t)16 * 512;

    f32x4 acc[4][4] = {};

    auto stage = [&](int it, int buf) {
        const int k0 = it * 32;
        gload_lds16(srcA0 + k0, &Al[buf][w * 32][0]);
        gload_lds16(srcA1 + k0, &Al[buf][w * 32 + 16][0]);
        gload_lds16(srcW0 + k0, &Wl[buf][w * 32][0]);
        gload_lds16(srcW1 + k0, &Wl[buf][w * 32 + 16][0]);
    };

    // prologue: stages 0,1 in flight; wait for stage 0 only
    stage(0, 0);
    stage(1, 1);
    asm volatile("s_waitcnt vmcnt(4)" ::: "memory");
    raw_barrier();

    const int key = (nl >> 1) & 3;
    int bcur = 0, bpre = 2;             // buffer for step i, and for step i+2
    for (int it = 0; it < 16; ++it) {
        if (it < 14) stage(it + 2, bpre);
        bf16x8 a[4], bb[4];
        #pragma unroll
        for (int am = 0; am < 4; ++am)
            a[am] = *reinterpret_cast<const bf16x8*>(
                &Al[bcur][wr * 64 + am * 16 + nl][(quad ^ key) * 8]);
        #pragma unroll
        for (int bn = 0; bn < 4; ++bn)
            bb[bn] = *reinterpret_cast<const bf16x8*>(
                &Wl[bcur][wc * 64 + bn * 16 + nl][(quad ^ key) * 8]);
        #pragma unroll
        for (int am = 0; am < 4; ++am)
            #pragma unroll
            for (int bn = 0; bn < 4; ++bn)
                acc[am][bn] = __builtin_amdgcn_mfma_f32_16x16x32_bf16(
                    a[am], bb[bn], acc[am][bn], 0, 0, 0);
        if (it < 14)       asm volatile("s_waitcnt vmcnt(4)" ::: "memory");
        else if (it == 14) asm volatile("s_waitcnt vmcnt(0)" ::: "memory");
        raw_barrier();
        bcur = (bcur == 2) ? 0 : bcur + 1;
        bpre = (bpre == 2) ? 0 : bpre + 1;
    }

    // ---- staged coalesced epilogue (all LDS dead; barrier passed) ----
    if (!trans) {
        short (*Cl)[136] = reinterpret_cast<short (*)[136]>(smem);  // 34.8 KB
        #pragma unroll
        for (int am = 0; am < 4; ++am)
            #pragma unroll
            for (int bn = 0; bn < 4; ++bn)
                #pragma unroll
                for (int r = 0; r < 4; ++r)
                    Cl[wr * 64 + am * 16 + quad * 4 + r][wc * 64 + bn * 16 + nl] =
                        (short)f2b(acc[am][bn][r] * alpha);
        __syncthreads();
        const int lr = tid >> 1;            // 0..127 (m row)
        const int ch = (tid & 1) * 64;      // short col half
        unsigned short* cp = C + (size_t)(m0g + lr) * 512 + n0 + ch;
        #pragma unroll
        for (int j = 0; j < 8; ++j)
            *reinterpret_cast<int4*>(cp + j * 8) =
                *reinterpret_cast<const int4*>(&Cl[lr][ch + j * 8]);
    } else {
        short (*Tl)[136] = reinterpret_cast<short (*)[136]>(smem);  // 34.8 KB
        #pragma unroll
        for (int am = 0; am < 4; ++am)
            #pragma unroll
            for (int bn = 0; bn < 4; ++bn) {
                int* dst = reinterpret_cast<int*>(
                    &Tl[wc * 64 + bn * 16 + nl][wr * 64 + am * 16 + quad * 4]);
                dst[0] = pack2bf(acc[am][bn][0], acc[am][bn][1]);
                dst[1] = pack2bf(acc[am][bn][2], acc[am][bn][3]);
            }
        __syncthreads();
        const int bq = m0g >> 11;
        const int t0 = m0g & 2047;
        const int nr = tid >> 1;            // 0..127 (n row)
        const int tc = (tid & 1) * 64;      // t chunk half
        unsigned short* vp = C + (size_t)(bq * 512 + n0 + nr) * T_SEQ + t0 + tc;
        #pragma unroll
        for (int j = 0; j < 8; ++j)
            *reinterpret_cast<int4*>(vp + j * 8) =
                *reinterpret_cast<const int4*>(&Tl[nr][tc + j * 8]);
    }
}

// ---------------------------------------------------------------------------
// Fused output projections (big path), 128x128 / 4x4-blocked (R8 version).
// A = AO bf16 via gload_lds; W fp32 reg-staged -> swizzled bf16 LDS; fp32 C
// staged through LDS, plain coalesced stores. 2 blocks/CU.
// Grid 512 = 2 z x 64 mt x 4 nh, bijective XCD swizzle (q=64).
// ---------------------------------------------------------------------------
__global__ __launch_bounds__(256, 2)
void out_fused(const unsigned short* __restrict__ AO1, const float* __restrict__ Wo1,
               float* __restrict__ C1,
               const unsigned short* __restrict__ AO2, const float* __restrict__ Wo2,
               float* __restrict__ C2)
{
    __shared__ __align__(16) char smem[67584];
    short (*Al)[128][64] = reinterpret_cast<short (*)[128][64]>(smem);          // 32 KB
    short (*Wl)[128][64] = reinterpret_cast<short (*)[128][64]>(smem + 32768);  // 32 KB

    const int o   = blockIdx.x;              // 512
    const int wg  = (o & 7) * 64 + (o >> 3); // bijective, 512 % 8 == 0
    const int z   = wg >> 8;
    const int idx = wg & 255;
    const int nh  = idx & 3;
    const int mt  = idx >> 2;

    const unsigned short* A = z ? AO2 : AO1;
    const float* W = z ? Wo2 : Wo1;
    float* C = z ? C2 : C1;

    const int tid  = threadIdx.x;
    const int w    = tid >> 6;
    const int wr   = w >> 1;
    const int wc   = w & 1;
    const int lane = tid & 63;
    const int nl   = lane & 15;
    const int quad = lane >> 4;
    const int r8   = lane >> 3;
    const int cg   = (lane & 7) ^ r8;

    const int m0g = mt * 128;
    const int n0  = nh * 128;

    const unsigned short* Ab = A + (size_t)m0g * 512 + cg * 8;

    // W staging: thread covers row tid>>1 (128 rows, 2 threads/row), 32
    // contiguous floats at k0 + (tid&1)*32. Swizzled bf16 store: logical
    // slot (tid&1)*4 + (j>>1), offset (j&1)*4 shorts, phys = slot^(row&7).
    const int rw_ = tid >> 1;
    const int ch_ = (tid & 1) * 32;
    const int key = rw_ & 7;

    f32x4 acc[4][4] = {};
    float4 wreg[8];

    auto stageA = [&](int it, int buf) {
        const int k0 = it * 64;
        #pragma unroll
        for (int g = 0; g < 4; ++g) {
            const int rr = w * 32 + g * 8;
            gload_lds16(Ab + (size_t)(rr + r8) * 512 + k0, &Al[buf][rr][0]);
        }
    };
    auto wload = [&](int it) {
        const float* wp = W + (size_t)(n0 + rw_) * 512 + it * 64 + ch_;
        #pragma unroll
        for (int j = 0; j < 8; ++j)
            wreg[j] = *reinterpret_cast<const float4*>(wp + 4 * j);
    };
    auto wstore = [&](int buf) {
        #pragma unroll
        for (int j = 0; j < 8; ++j) {
            int2 pk;
            pk.x = pack2bf(wreg[j].x, wreg[j].y);
            pk.y = pack2bf(wreg[j].z, wreg[j].w);
            const int slot = ((tid & 1) * 4 + (j >> 1)) ^ key;
            *reinterpret_cast<int2*>(
                &Wl[buf][rw_][slot * 8 + (j & 1) * 4]) = pk;
        }
    };

    // prologue
    wload(0);
    stageA(0, 0);
    asm volatile("s_waitcnt vmcnt(0)" ::: "memory");
    wstore(0);
    __syncthreads();

    const int sw = nl & 7;
    for (int it = 0; it < 8; ++it) {
        const int buf = it & 1;
        if (it < 7) { stageA(it + 1, buf ^ 1); wload(it + 1); }
        #pragma unroll
        for (int kc = 0; kc < 2; ++kc) {
            bf16x8 a[4], bb[4];
            #pragma unroll
            for (int am = 0; am < 4; ++am)
                a[am] = *reinterpret_cast<const bf16x8*>(
                    &Al[buf][wr * 64 + am * 16 + nl][((kc * 4 + quad) ^ sw) * 8]);
            #pragma unroll
            for (int bn = 0; bn < 4; ++bn)
                bb[bn] = *reinterpret_cast<const bf16x8*>(
                    &Wl[buf][wc * 64 + bn * 16 + nl][((kc * 4 + quad) ^ sw) * 8]);
            #pragma unroll
            for (int am = 0; am < 4; ++am)
                #pragma unroll
                for (int bn = 0; bn < 4; ++bn)
                    acc[am][bn] = __builtin_amdgcn_mfma_f32_16x16x32_bf16(
                        a[am], bb[bn], acc[am][bn], 0, 0, 0);
        }
        asm volatile("s_waitcnt vmcnt(0)" ::: "memory");
        if (it < 7) wstore(buf ^ 1);
        __syncthreads();
    }

    // ---- fp32 epilogue staged through LDS, 256B/thread stores ----
    float (*Cl)[132] = reinterpret_cast<float (*)[132]>(smem);   // 67.6 KB
    #pragma unroll
    for (int am = 0; am < 4; ++am)
        #pragma unroll
        for (int bn = 0; bn < 4; ++bn)
            #pragma unroll
            for (int r = 0; r < 4; ++r)
                Cl[wr * 64 + am * 16 + quad * 4 + r][wc * 64 + bn * 16 + nl] =
                    acc[am][bn][r];
    __syncthreads();
    const int lr = tid >> 1;            // 0..127
    const int fc = (tid & 1) * 64;      // float col half
    float* cp = C + (size_t)(m0g + lr) * 512 + n0 + fc;
    #pragma unroll
    for (int j = 0; j < 16; ++j)
        *reinterpret_cast<float4*>(cp + j * 4) =
            *reinterpret_cast<const float4*>(&Cl[lr][fc + j * 4]);
}

// ---------------------------------------------------------------------------
// Fallback output projection (small-ws path only).
// ---------------------------------------------------------------------------
__global__ __launch_bounds__(256)
void out_proj(const unsigned short* __restrict__ AO1, const float* __restrict__ Wo1,
              float* __restrict__ C1,
              const unsigned short* __restrict__ AO2, const float* __restrict__ Wo2,
              float* __restrict__ C2, int zbase)
{
    const int z = zbase + blockIdx.z;
    const unsigned short* A = z ? AO2 : AO1;
    const float* W = z ? Wo2 : Wo1;
    float* C = z ? C2 : C1;

    MF_SETUP
    const unsigned short* ap = A + (size_t)(m0 + arow) * 512 + acol;
    const float* wp = W + (size_t)(n0 + arow) * 512 + acol;
    int4 ai[2];
    float4 wv[4];
    ai[0] = *reinterpret_cast<const int4*>(ap);
    ai[1] = *reinterpret_cast<const int4*>(ap + 8);
    #pragma unroll
    for (int j = 0; j < 4; ++j)
        wv[j] = *reinterpret_cast<const float4*>(wp + 4 * j);
    for (int it = 0; it < 8; ++it) {
        __syncthreads();
        *reinterpret_cast<int4*>(&Asm[arow][acol])     = ai[0];
        *reinterpret_cast<int4*>(&Asm[arow][acol + 8]) = ai[1];
        MF_WRITE_W
        __syncthreads();
        if (it < 7) {
            const unsigned short* apn = ap + (it + 1) * 64;
            const float* wpn = wp + (it + 1) * 64;
            ai[0] = *reinterpret_cast<const int4*>(apn);
            ai[1] = *reinterpret_cast<const int4*>(apn + 8);
            #pragma unroll
            for (int j = 0; j < 4; ++j)
                wv[j] = *reinterpret_cast<const float4*>(wpn + 4 * j);
        }
        MF_MMA_LOOP
    }
    #pragma unroll
    for (int c = 0; c < 4; ++c)
        #pragma unroll
        for (int r = 0; r < 4; ++r)
            C[(size_t)(m0 + w4 * 16 + quad * 4 + r) * 512 + n0 + c * 16 + nl] =
                acc[c][r];
}

// ---------------------------------------------------------------------------
// MFMA flash attention, both directions in one dispatch (blockIdx.y >> 5).
// Block = 8 waves / 512 threads = one (dir,b,h,128-row q-tile); wave owns 16
// q rows. K/V LDS tiles shared by all 8 waves; LDS 48 KB -> 3 blocks/CU.
// K/V staged via global_load_lds (double-buffered, swizzled); FIXED-MAX
// softmax (log2-domain, m=0 exact-equivalent); mask bias rides the QK MFMA
// C-input; l-reduce once at epilogue; s_setprio(1) wraps PV cluster.
// AO aliases Q (block-local RAW only).
// ---------------------------------------------------------------------------
__global__ __launch_bounds__(512)
void attn_mfma(const unsigned short* Q1x, const unsigned short* __restrict__ K1x,
               const unsigned short* __restrict__ V1x, const float* __restrict__ b1x,
               unsigned short* AO1x,
               const unsigned short* Q2x, const unsigned short* __restrict__ K2x,
               const unsigned short* __restrict__ V2x, const float* __restrict__ b2x,
               unsigned short* AO2x)
{
    __shared__ short Kl[2][64][64];   // [buf][kv_row][d] (swizzled 16B slots)
    __shared__ short Vl[2][64][64];   // [buf][d_row][kv] (swizzled 16B slots)
    __shared__ short Pl[8][16][64];   // pitch 64 + slot-XOR; total LDS = 48 KB

    const int dir = blockIdx.y >> 5;
    const unsigned short* Q  = dir ? Q2x : Q1x;
    const unsigned short* K  = dir ? K2x : K1x;
    const unsigned short* Vt = dir ? V2x : V1x;
    const float* biasD       = dir ? b2x : b1x;
    unsigned short* AO       = dir ? AO2x : AO1x;

    const int tid  = threadIdx.x;
    const int w    = tid >> 6;              // 0..7
    const int lane = tid & 63;
    const int nl   = lane & 15;
    const int quad = lane >> 4;
    const int qt = blockIdx.x;              // 0..15 (128-row q-tiles)
    const int bh = blockIdx.y & 31;         // 0..31
    const int b = bh >> 3, h = bh & 7;
    const size_t tb = (size_t)b * (T_SEQ * 512);
    const float* biasB = biasD + b * T_SEQ;

    const int r8 = lane >> 3;
    const int cg = (lane & 7) ^ r8;
    const int sr = w * 8;                   // this wave's staging row base

    // Q B-frags (n=lane&15 => q row, k=quad*8+j)
    const unsigned short* qp = Q + tb + (size_t)(qt * 128 + w * 16 + nl) * 512 + h * 64 + quad * 8;
    const bf16x8 qb0 = ldg8(qp);
    const bf16x8 qb1 = ldg8(qp + 32);

    float l_run = 0.0f;   // lane-local partial (this lane's kv slots only)
    f32x4 o[4] = {};   // O^T: o[sd] holds d = sd*16+quad*4+r (row), q = nl (col)

    // prologue: stage tile 0 into buffer 0
    gload_lds16(K  + tb + (size_t)(sr + r8) * 512 + h * 64 + cg * 8, &Kl[0][sr][0]);
    gload_lds16(Vt + (size_t)(b * 512 + h * 64 + sr + r8) * T_SEQ + cg * 8, &Vl[0][sr][0]);
    asm volatile("s_waitcnt vmcnt(0)" ::: "memory");
    __syncthreads();

    const int swz = nl & 7;

    for (int kt = 0; kt < 32; ++kt) {
        const int cur = kt & 1;
        short (*Kb)[64] = Kl[cur];
        short (*Vb)[64] = Vl[cur];

        // issue next tile's DMA (lands before next iteration's barrier)
        if (kt < 31) {
            short (*Kn)[64] = Kl[cur ^ 1];
            short (*Vn)[64] = Vl[cur ^ 1];
            gload_lds16(K  + tb + (size_t)((kt + 1) * 64 + sr + r8) * 512 + h * 64 + cg * 8, &Kn[sr][0]);
            gload_lds16(Vt + (size_t)(b * 512 + h * 64 + sr + r8) * T_SEQ + (size_t)(kt + 1) * 64 + cg * 8, &Vn[sr][0]);
        }

        // scores S^T[kv][q] (log2 domain); mask bias enters as MFMA C-input
        float p[4][4];
        #pragma unroll
        for (int s = 0; s < 4; ++s) {
            const bf16x8 k0 = *reinterpret_cast<const bf16x8*>(&Kb[s * 16 + nl][(quad ^ swz) * 8]);
            const bf16x8 k1 = *reinterpret_cast<const bf16x8*>(&Kb[s * 16 + nl][((4 + quad) ^ swz) * 8]);
            const float4 bb = *reinterpret_cast<const float4*>(
                &biasB[kt * 64 + s * 16 + quad * 4]);
            f32x4 z = {bb.x, bb.y, bb.z, bb.w};
            z = __builtin_amdgcn_mfma_f32_16x16x32_bf16(k0, qb0, z, 0, 0, 0);
            z = __builtin_amdgcn_mfma_f32_16x16x32_bf16(k1, qb1, z, 0, 0, 0);
            p[s][0] = fexp2(z[0]);
            p[s][1] = fexp2(z[1]);
            p[s][2] = fexp2(z[2]);
            p[s][3] = fexp2(z[3]);
            l_run += p[s][0] + p[s][1] + p[s][2] + p[s][3];
        }

        // P -> LDS [q][kv], pitch 64 with 16B-slot XOR (key = nl&7).
        #pragma unroll
        for (int s = 0; s < 4; ++s) {
            int2 pk;
            pk.x = pack2bf(p[s][0], p[s][1]);
            pk.y = pack2bf(p[s][2], p[s][3]);
            const int slot = (2 * s + (quad >> 1)) ^ swz;
            *reinterpret_cast<int2*>(&Pl[w][nl][slot * 8 + (quad & 1) * 4]) = pk;
        }

        // O^T += V^T · P^T (pa read back with the same slot-XOR)
        const bf16x8 pa0 = *reinterpret_cast<const bf16x8*>(&Pl[w][nl][(quad ^ swz) * 8]);
        const bf16x8 pa1 = *reinterpret_cast<const bf16x8*>(&Pl[w][nl][((4 + quad) ^ swz) * 8]);
        __builtin_amdgcn_s_setprio(1);
        #pragma unroll
        for (int sd = 0; sd < 4; ++sd) {
            const bf16x8 v0 = *reinterpret_cast<const bf16x8*>(&Vb[sd * 16 + nl][(quad ^ swz) * 8]);
            const bf16x8 v1 = *reinterpret_cast<const bf16x8*>(&Vb[sd * 16 + nl][((4 + quad) ^ swz) * 8]);
            o[sd] = __builtin_amdgcn_mfma_f32_16x16x32_bf16(v0, pa0, o[sd], 0, 0, 0);
            o[sd] = __builtin_amdgcn_mfma_f32_16x16x32_bf16(v1, pa1, o[sd], 0, 0, 0);
        }
        __builtin_amdgcn_s_setprio(0);

        // drain this iteration's DMA, release buffers
        asm volatile("s_waitcnt vmcnt(0)" ::: "memory");
        __syncthreads();
    }

    // epilogue: reduce l across the 4 kv-quadrant lanes ONCE, then store
    l_run += __shfl_xor(l_run, 16);
    l_run += __shfl_xor(l_run, 32);
    const float inv = 1.0f / l_run;
    unsigned short* ob = AO + tb + (size_t)(qt * 128 + w * 16 + nl) * 512 + h * 64 + quad * 4;
    #pragma unroll
    for (int sd = 0; sd < 4; ++sd) {
        ushort4 o4;
        o4.x = f2b(o[sd][0] * inv);
        o4.y = f2b(o[sd][1] * inv);
        o4.z = f2b(o[sd][2] * inv);
        o4.w = f2b(o[sd][3] * inv);
        *reinterpret_cast<ushort4*>(ob + sd * 16) = o4;
    }
}

extern "C" void kernel_launch(void* const* d_in, const int* in_sizes, int n_in,
                              void* d_out, int out_size, void* d_ws, size_t ws_size,
                              hipStream_t stream) {
    const float* skel = (const float*)d_in[0];
    const float* sens = (const float*)d_in[1];
    const int* mask_skel = (const int*)d_in[2];
    const int* mask_sens = (const int*)d_in[3];
    const float* Wq_s2e = (const float*)d_in[4];
    const float* Wk_e   = (const float*)d_in[5];
    const float* Wv_e   = (const float*)d_in[6];
    const float* Wq_e2s = (const float*)d_in[7];
    const float* Wk_s   = (const float*)d_in[8];
    const float* Wv_s   = (const float*)d_in[9];
    const float* Wo_s   = (const float*)d_in[10];
    const float* Wo_e   = (const float*)d_in[11];
    float* out = (float*)d_out;   // fp32: [e2s (4M)][s2e (4M)]

    unsigned short* Q1 = (unsigned short*)d_ws;    // dir0 Q / AO (aliased)
    unsigned short* K1 = Q1 + N_TOK;
    unsigned short* V1 = K1 + N_TOK;               // Vt

    const bool big = ws_size >= (size_t)6 * N_TOK * sizeof(unsigned short);

    if (big) {
        unsigned short* Q2 = V1 + N_TOK;
        unsigned short* K2 = Q2 + N_TOK;
        unsigned short* V2 = K2 + N_TOK;
        // bf16+bias scratch lives in d_out (dead until out_fused, stream order)
        unsigned short* SC  = (unsigned short*)d_out;
        unsigned short* skb = SC;
        unsigned short* snb = SC + N_TOK;
        unsigned short* wb  = SC + 2 * (size_t)N_TOK;
        float* biasS = (float*)(SC + 2 * (size_t)N_TOK + 6 * W_ELEM);
        float* bias0 = biasS;                 // dir0 <- mask_sens
        float* bias1 = biasS + 4 * T_SEQ;     // dir1 <- mask_skel
        prep_bias<<<dim3(8), 256, 0, stream>>>(mask_sens, mask_skel, biasS);
        to_bf16<<<dim3(4864), 256, 0, stream>>>(
            skel, sens, Wq_s2e, Wk_e, Wv_e, Wq_e2s, Wk_s, Wv_s, SC);
        // dir0 = s2e (out slot 1), dir1 = e2s (out slot 0)
        proj_fused<<<dim3(1536), 256, 0, stream>>>(
            skb, snb, wb, Q1, K1, V1, Q2, K2, V2);
        attn_mfma<<<dim3(16, 64), 512, 0, stream>>>(
            Q1, K1, V1, bias0, Q1,
            Q2, K2, V2, bias1, Q2);
        out_fused<<<dim3(512), 256, 0, stream>>>(
            Q1, Wo_e, out + N_TOK, Q2, Wo_s, out);
    } else {
        // sequential fallback: reuse the 3-buffer workspace per direction.
        // bias scratch in the e2s half of out (overwritten by the LAST
        // out_proj, after its final use).
        float* bias0 = out;                   // dir0 <- mask_sens
        float* bias1 = out + 8192;            // dir1 <- mask_skel
        prep_bias<<<dim3(8), 256, 0, stream>>>(mask_sens, mask_skel, bias0);
        proj_all<<<dim3(8, 128, 3), 256, 0, stream>>>(
            skel, sens, Wq_s2e, Wk_e, Wv_e, Wq_e2s, Wk_s, Wv_s,
            Q1, K1, V1, Q1, K1, V1, 0);
        attn_mfma<<<dim3(16, 32), 512, 0, stream>>>(
            Q1, K1, V1, bias0, Q1, Q1, K1, V1, bias0, Q1);
        out_proj<<<dim3(8, 128, 1), 256, 0, stream>>>(
            Q1, Wo_e, out + N_TOK, Q1, Wo_s, out, 0);
        proj_all<<<dim3(8, 128, 3), 256, 0, stream>>>(
            skel, sens, Wq_s2e, Wk_e, Wv_e, Wq_e2s, Wk_s, Wv_s,
            Q1, K1, V1, Q1, K1, V1, 3);
        attn_mfma<<<dim3(16, 32), 512, 0, stream>>>(
            Q1, K1, V1, bias1, Q1, Q1, K1, V1, bias1, Q1);
        out_proj<<<dim3(8, 128, 1), 256, 0, stream>>>(
            Q1, Wo_s, out, Q1, Wo_s, out, 1);
    }
}

// Round 12
// 273.639 us; speedup vs baseline: 1.5820x; 1.0375x over previous
//
#include <hip/hip_runtime.h>
#include <hip/hip_bf16.h>

// Problem constants: B=4, T=2048, D=512, H=8, DK=64
#define T_SEQ 2048
#define N_TOK 4194304   // 4 * 2048 * 512 elements per [B,T,D] tensor
#define W_ELEM 262144   // 512*512

// Inputs: FLOAT32. Output: FLOAT32, (e2s, s2e) concat.
// ws (fused path, 48 MB): Q1,K1 [B,T,512] bf16; Vt1 [B,512,T] bf16; Q2,K2,Vt2.
// AO aliases Q per direction. After attn, K1 is reused for bf16 Wo scratch.
// Fallback (<48 MB ws): 24 MB, sequential.
// Big path: d_out doubles as scratch (skel,sens bf16; 6 proj W bf16; bias
// floats) until out_fused runs (strict stream order).

typedef float f32x4  __attribute__((ext_vector_type(4)));
typedef short bf16x8 __attribute__((ext_vector_type(8)));

// 1.5/sqrt(64) * log2(e): attention logits are produced in log2 domain so
// softmax uses bare v_exp_f32 (exp2) with no per-element multiply.
#define SCALE_Q 0.27050532f

__device__ __forceinline__ unsigned short f2b(float f) {
    __hip_bfloat16 h = __float2bfloat16(f);
    return *reinterpret_cast<unsigned short*>(&h);
}

__device__ __forceinline__ int pack2bf(float lo, float hi) {
    return ((int)f2b(hi) << 16) | (int)f2b(lo);
}

__device__ __forceinline__ bf16x8 ldg8(const unsigned short* p) {
    union { int4 i; bf16x8 b; } u;
    u.i = *reinterpret_cast<const int4*>(p);
    return u.b;
}

__device__ __forceinline__ float fexp2(float x) {
#if __has_builtin(__builtin_amdgcn_exp2f)
    return __builtin_amdgcn_exp2f(x);
#else
    return exp2f(x);
#endif
}

// async global->LDS DMA, 16B per lane; LDS dest = wave-uniform base + lane*16
typedef unsigned int u32_g __attribute__((address_space(1)));
typedef unsigned int u32_l __attribute__((address_space(3)));
__device__ __forceinline__ void gload_lds16(const void* g, void* l) {
    __builtin_amdgcn_global_load_lds((const u32_g*)g, (u32_l*)l, 16, 0, 0);
}

// raw barrier (no compiler-inserted vmcnt(0) drain) with scheduling fences
__device__ __forceinline__ void raw_barrier() {
    __builtin_amdgcn_sched_barrier(0);
    __builtin_amdgcn_s_barrier();
    __builtin_amdgcn_sched_barrier(0);
}

// ---------------------------------------------------------------------------
// mask -> additive float bias precompute: dst = [2][B][T_SEQ] floats (64 KB).
// dir0 <- mask_sens, dir1 <- mask_skel.
// ---------------------------------------------------------------------------
__global__ __launch_bounds__(256)
void prep_bias(const int* __restrict__ ms, const int* __restrict__ mk,
               float* __restrict__ dst)
{
    const int i = (blockIdx.x * 256 + threadIdx.x) * 8;   // 16384 total
    const int* m = (i >> 13) ? mk : ms;
    const int rem = i & 8191;
    const int4 a = *reinterpret_cast<const int4*>(&m[rem]);
    const int4 b = *reinterpret_cast<const int4*>(&m[rem + 4]);
    float4 f0, f1;
    f0.x = a.x ? 0.0f : -3e38f; f0.y = a.y ? 0.0f : -3e38f;
    f0.z = a.z ? 0.0f : -3e38f; f0.w = a.w ? 0.0f : -3e38f;
    f1.x = b.x ? 0.0f : -3e38f; f1.y = b.y ? 0.0f : -3e38f;
    f1.z = b.z ? 0.0f : -3e38f; f1.w = b.w ? 0.0f : -3e38f;
    *reinterpret_cast<float4*>(&dst[i])     = f0;
    *reinterpret_cast<float4*>(&dst[i + 4]) = f1;
}

// ---------------------------------------------------------------------------
// fp32 -> bf16 pre-conversion, exact 1D grid (4864 blocks):
// [0,2048) skel, [2048,4096) sens, then 6 x 128 blocks for proj weights.
// dst layout: [skel 4M][sens 4M][W0..W5 x 256K] shorts (19 MB).
// ---------------------------------------------------------------------------
__global__ __launch_bounds__(256)
void to_bf16(const float* __restrict__ s0, const float* __restrict__ s1,
             const float* __restrict__ w0, const float* __restrict__ w1,
             const float* __restrict__ w2, const float* __restrict__ w3,
             const float* __restrict__ w4, const float* __restrict__ w5,
             unsigned short* __restrict__ dst)
{
    const int bid = blockIdx.x;
    int y, x;
    if (bid < 4096) { y = bid >> 11; x = bid & 2047; }
    else { const int t = bid - 4096; y = 2 + (t >> 7); x = t & 127; }
    const float* src;
    size_t off;
    switch (y) {
        case 0: src = s0; off = 0;      break;
        case 1: src = s1; off = N_TOK;  break;
        case 2: src = w0; off = 2 * (size_t)N_TOK;              break;
        case 3: src = w1; off = 2 * (size_t)N_TOK + 1 * W_ELEM; break;
        case 4: src = w2; off = 2 * (size_t)N_TOK + 2 * W_ELEM; break;
        case 5: src = w3; off = 2 * (size_t)N_TOK + 3 * W_ELEM; break;
        case 6: src = w4; off = 2 * (size_t)N_TOK + 4 * W_ELEM; break;
        default: src = w5; off = 2 * (size_t)N_TOK + 5 * W_ELEM; break;
    }
    const int idx = (x * 256 + threadIdx.x) * 8;
    const float4 a = *reinterpret_cast<const float4*>(src + idx);
    const float4 b = *reinterpret_cast<const float4*>(src + idx + 4);
    int4 o;
    o.x = pack2bf(a.x, a.y); o.y = pack2bf(a.z, a.w);
    o.z = pack2bf(b.x, b.y); o.w = pack2bf(b.z, b.w);
    *reinterpret_cast<int4*>(dst + off + idx) = o;
}

// ---------------------------------------------------------------------------
// Wo fp32 -> bf16 (runs after attn; dst = dead K1 ws region, 1 MB).
// dst layout: [Wo_e 256K][Wo_s 256K] shorts. Grid 256.
// ---------------------------------------------------------------------------
__global__ __launch_bounds__(256)
void wo_bf16(const float* __restrict__ we, const float* __restrict__ wsrc,
             unsigned short* __restrict__ dst)
{
    const int i = (blockIdx.x * 256 + threadIdx.x) * 8;   // 0..524280
    const float* src = (i >= W_ELEM) ? wsrc : we;
    const int rem = i & (W_ELEM - 1);
    const float4 a = *reinterpret_cast<const float4*>(src + rem);
    const float4 b = *reinterpret_cast<const float4*>(src + rem + 4);
    int4 o;
    o.x = pack2bf(a.x, a.y); o.y = pack2bf(a.z, a.w);
    o.z = pack2bf(b.x, b.y); o.w = pack2bf(b.z, b.w);
    *reinterpret_cast<int4*>(dst + i) = o;
}

// ---------------------------------------------------------------------------
// Shared MFMA-GEMM tile machinery (fallback proj + fallback out_proj).
// ---------------------------------------------------------------------------
#define MF_SETUP                                                               \
    __shared__ short Asm[64][72];                                              \
    __shared__ short Wsm[64][72];                                              \
    const int tid  = threadIdx.x;                                              \
    const int lane = tid & 63;                                                 \
    const int w4   = tid >> 6;                                                 \
    const int nl   = lane & 15;                                                \
    const int quad = lane >> 4;                                                \
    const int n0 = blockIdx.x * 64;                                            \
    const int m0 = blockIdx.y * 64;                                            \
    const int arow = tid >> 2;                                                 \
    const int acol = (tid & 3) * 16;                                           \
    f32x4 acc[4] = {};

#define MF_WRITE_W                                                             \
    {                                                                          \
        int4 x;                                                                \
        x.x = pack2bf(wv[0].x, wv[0].y); x.y = pack2bf(wv[0].z, wv[0].w);      \
        x.z = pack2bf(wv[1].x, wv[1].y); x.w = pack2bf(wv[1].z, wv[1].w);      \
        *reinterpret_cast<int4*>(&Wsm[arow][acol]) = x;                        \
        x.x = pack2bf(wv[2].x, wv[2].y); x.y = pack2bf(wv[2].z, wv[2].w);      \
        x.z = pack2bf(wv[3].x, wv[3].y); x.w = pack2bf(wv[3].z, wv[3].w);      \
        *reinterpret_cast<int4*>(&Wsm[arow][acol + 8]) = x;                    \
    }

#define MF_MMA_LOOP                                                            \
    _Pragma("unroll")                                                          \
    for (int kc = 0; kc < 2; ++kc) {                                           \
        const bf16x8 a = *reinterpret_cast<const bf16x8*>(                     \
            &Asm[w4 * 16 + nl][kc * 32 + quad * 8]);                           \
        _Pragma("unroll")                                                      \
        for (int c = 0; c < 4; ++c) {                                          \
            const bf16x8 bf = *reinterpret_cast<const bf16x8*>(                \
                &Wsm[c * 16 + nl][kc * 32 + quad * 8]);                        \
            acc[c] = __builtin_amdgcn_mfma_f32_16x16x32_bf16(a, bf, acc[c],    \
                                                             0, 0, 0);         \
        }                                                                      \
    }

#define MF_CWRITE_PROJ                                                         \
    if (!trans) {                                                              \
        _Pragma("unroll")                                                      \
        for (int c = 0; c < 4; ++c)                                            \
            _Pragma("unroll")                                                  \
            for (int r = 0; r < 4; ++r)                                        \
                C[(size_t)(m0 + w4 * 16 + quad * 4 + r) * 512 + n0 + c * 16 + nl] = \
                    f2b(acc[c][r] * alpha);                                    \
    } else {                                                                   \
        const int b  = m0 >> 11;                                               \
        const int t0 = (m0 & 2047) + w4 * 16 + quad * 4;                       \
        _Pragma("unroll")                                                      \
        for (int c = 0; c < 4; ++c) {                                          \
            const int n = n0 + c * 16 + nl;                                    \
            ushort4 o;                                                         \
            o.x = f2b(acc[c][0]);                                              \
            o.y = f2b(acc[c][1]);                                              \
            o.z = f2b(acc[c][2]);                                              \
            o.w = f2b(acc[c][3]);                                              \
            *reinterpret_cast<ushort4*>(C + (size_t)(b * 512 + n) * T_SEQ + t0) = o; \
        }                                                                      \
    }

// ---------------------------------------------------------------------------
// fp32-input projections (fallback path only).
// ---------------------------------------------------------------------------
__global__ __launch_bounds__(256)
void proj_all(const float* __restrict__ skel, const float* __restrict__ sens,
              const float* __restrict__ Wq1, const float* __restrict__ Wk1,
              const float* __restrict__ Wv1, const float* __restrict__ Wq2,
              const float* __restrict__ Wk2, const float* __restrict__ Wv2,
              unsigned short* __restrict__ Q1, unsigned short* __restrict__ K1,
              unsigned short* __restrict__ Vt1, unsigned short* __restrict__ Q2,
              unsigned short* __restrict__ K2, unsigned short* __restrict__ Vt2,
              int zbase)
{
    const int z = zbase + blockIdx.z;
    const float* A; const float* W; unsigned short* C;
    float alpha = 1.0f; bool trans = false;
    switch (z) {
        case 0:  A = skel; W = Wq1; C = Q1; alpha = SCALE_Q; break;
        case 1:  A = sens; W = Wk1; C = K1; break;
        case 2:  A = sens; W = Wv1; C = Vt1; trans = true; break;
        case 3:  A = sens; W = Wq2; C = Q2; alpha = SCALE_Q; break;
        case 4:  A = skel; W = Wk2; C = K2; break;
        default: A = skel; W = Wv2; C = Vt2; trans = true; break;
    }

    MF_SETUP
    const float* ap = A + (size_t)(m0 + arow) * 512 + acol;
    const float* wp = W + (size_t)(n0 + arow) * 512 + acol;
    float4 av[4], wv[4];
    #pragma unroll
    for (int j = 0; j < 4; ++j) {
        av[j] = *reinterpret_cast<const float4*>(ap + 4 * j);
        wv[j] = *reinterpret_cast<const float4*>(wp + 4 * j);
    }
    for (int it = 0; it < 8; ++it) {
        __syncthreads();
        {
            int4 x;
            x.x = pack2bf(av[0].x, av[0].y); x.y = pack2bf(av[0].z, av[0].w);
            x.z = pack2bf(av[1].x, av[1].y); x.w = pack2bf(av[1].z, av[1].w);
            *reinterpret_cast<int4*>(&Asm[arow][acol]) = x;
            x.x = pack2bf(av[2].x, av[2].y); x.y = pack2bf(av[2].z, av[2].w);
            x.z = pack2bf(av[3].x, av[3].y); x.w = pack2bf(av[3].z, av[3].w);
            *reinterpret_cast<int4*>(&Asm[arow][acol + 8]) = x;
        }
        MF_WRITE_W
        __syncthreads();
        if (it < 7) {
            const float* apn = ap + (it + 1) * 64;
            const float* wpn = wp + (it + 1) * 64;
            #pragma unroll
            for (int j = 0; j < 4; ++j) {
                av[j] = *reinterpret_cast<const float4*>(apn + 4 * j);
                wv[j] = *reinterpret_cast<const float4*>(wpn + 4 * j);
            }
        }
        MF_MMA_LOOP
    }
    MF_CWRITE_PROJ
}

// ---------------------------------------------------------------------------
// Fused all-6-projection GEMM (big path), 128x128 tile, 4 waves (2x2), 4x4
// register blocking. BK=32 with a 3-buffer counted-vmcnt pipeline (T3+T4):
// issue stage i+2, compute stage i, wait vmcnt(4) at a RAW barrier (stage
// i+1 landed, i+2 still flying). LDS 48 KB -> 3 blocks/CU. Plain C stores.
// Swizzle (4 slots/row): read slot = quad ^ ((nl>>1)&3); global source
// pre-swizzled cg = (l&3)^((l>>3)&3).
// ---------------------------------------------------------------------------
__global__ __launch_bounds__(256, 3)
void proj_fused(const unsigned short* __restrict__ skb,
                const unsigned short* __restrict__ snb,
                const unsigned short* __restrict__ wball,
                unsigned short* __restrict__ Q1, unsigned short* __restrict__ K1,
                unsigned short* __restrict__ Vt1, unsigned short* __restrict__ Q2,
                unsigned short* __restrict__ K2, unsigned short* __restrict__ Vt2)
{
    __shared__ __align__(16) char smem[49152];
    short (*Al)[128][32] = reinterpret_cast<short (*)[128][32]>(smem);           // 24 KB
    short (*Wl)[128][32] = reinterpret_cast<short (*)[128][32]>(smem + 24576);   // 24 KB

    // bijective XCD swizzle: nwg=1536, 8 XCDs, q=192
    const int o   = blockIdx.x;
    const int wg  = (o & 7) * 192 + (o >> 3);
    const int z   = wg >> 8;            // 0..5
    const int idx = wg & 255;
    const int nh  = idx & 3;            // n-tile, fastest: A-tile L2 reuse
    const int mt  = idx >> 2;           // 0..63

    const unsigned short* A = (z == 0 || z >= 4) ? skb : snb;
    const unsigned short* W = wball + (size_t)z * W_ELEM;
    unsigned short* C;
    switch (z) {
        case 0: C = Q1;  break;
        case 1: C = K1;  break;
        case 2: C = Vt1; break;
        case 3: C = Q2;  break;
        case 4: C = K2;  break;
        default: C = Vt2; break;
    }
    const bool trans = (z == 2 || z == 5);
    const float alpha = (z == 0 || z == 3) ? SCALE_Q : 1.0f;

    const int tid  = threadIdx.x;
    const int w    = tid >> 6;
    const int wr   = w >> 1;            // wave row (0..1)
    const int wc   = w & 1;             // wave col (0..1)
    const int lane = tid & 63;
    const int nl   = lane & 15;
    const int quad = lane >> 4;
    const int rof  = lane >> 2;                      // row offset in 16-row group
    const int cg   = (lane & 3) ^ ((lane >> 3) & 3); // inverse-swizzled chunk

    const int m0g = mt * 128;
    const int n0  = nh * 128;

    // per-thread source bases: two 16-row groups for A and for W
    const unsigned short* srcA0 = A + (size_t)(m0g + w * 32 + rof) * 512 + cg * 8;
    const unsigned short* srcA1 = srcA0 + (size_t)16 * 512;
    const unsigned short* srcW0 = W + (size_t)(n0 + w * 32 + rof) * 512 + cg * 8;
    const unsigned short* srcW1 = srcW0 + (size_t)16 * 512;

    f32x4 acc[4][4] = {};

    auto stage = [&](int it, int buf) {
        const int k0 = it * 32;
        gload_lds16(srcA0 + k0, &Al[buf][w * 32][0]);
        gload_lds16(srcA1 + k0, &Al[buf][w * 32 + 16][0]);
        gload_lds16(srcW0 + k0, &Wl[buf][w * 32][0]);
        gload_lds16(srcW1 + k0, &Wl[buf][w * 32 + 16][0]);
    };

    // prologue: stages 0,1 in flight; wait for stage 0 only
    stage(0, 0);
    stage(1, 1);
    asm volatile("s_waitcnt vmcnt(4)" ::: "memory");
    raw_barrier();

    const int key = (nl >> 1) & 3;
    int bcur = 0, bpre = 2;             // buffer for step i, and for step i+2
    for (int it = 0; it < 16; ++it) {
        if (it < 14) stage(it + 2, bpre);
        bf16x8 a[4], bb[4];
        #pragma unroll
        for (int am = 0; am < 4; ++am)
            a[am] = *reinterpret_cast<const bf16x8*>(
                &Al[bcur][wr * 64 + am * 16 + nl][(quad ^ key) * 8]);
        #pragma unroll
        for (int bn = 0; bn < 4; ++bn)
            bb[bn] = *reinterpret_cast<const bf16x8*>(
                &Wl[bcur][wc * 64 + bn * 16 + nl][(quad ^ key) * 8]);
        #pragma unroll
        for (int am = 0; am < 4; ++am)
            #pragma unroll
            for (int bn = 0; bn < 4; ++bn)
                acc[am][bn] = __builtin_amdgcn_mfma_f32_16x16x32_bf16(
                    a[am], bb[bn], acc[am][bn], 0, 0, 0);
        if (it < 14)       asm volatile("s_waitcnt vmcnt(4)" ::: "memory");
        else if (it == 14) asm volatile("s_waitcnt vmcnt(0)" ::: "memory");
        raw_barrier();
        bcur = (bcur == 2) ? 0 : bcur + 1;
        bpre = (bpre == 2) ? 0 : bpre + 1;
    }

    // ---- staged coalesced epilogue (all LDS dead; barrier passed) ----
    if (!trans) {
        short (*Cl)[136] = reinterpret_cast<short (*)[136]>(smem);  // 34.8 KB
        #pragma unroll
        for (int am = 0; am < 4; ++am)
            #pragma unroll
            for (int bn = 0; bn < 4; ++bn)
                #pragma unroll
                for (int r = 0; r < 4; ++r)
                    Cl[wr * 64 + am * 16 + quad * 4 + r][wc * 64 + bn * 16 + nl] =
                        (short)f2b(acc[am][bn][r] * alpha);
        __syncthreads();
        const int lr = tid >> 1;            // 0..127 (m row)
        const int ch = (tid & 1) * 64;      // short col half
        unsigned short* cp = C + (size_t)(m0g + lr) * 512 + n0 + ch;
        #pragma unroll
        for (int j = 0; j < 8; ++j)
            *reinterpret_cast<int4*>(cp + j * 8) =
                *reinterpret_cast<const int4*>(&Cl[lr][ch + j * 8]);
    } else {
        short (*Tl)[136] = reinterpret_cast<short (*)[136]>(smem);  // 34.8 KB
        #pragma unroll
        for (int am = 0; am < 4; ++am)
            #pragma unroll
            for (int bn = 0; bn < 4; ++bn) {
                int* dst = reinterpret_cast<int*>(
                    &Tl[wc * 64 + bn * 16 + nl][wr * 64 + am * 16 + quad * 4]);
                dst[0] = pack2bf(acc[am][bn][0], acc[am][bn][1]);
                dst[1] = pack2bf(acc[am][bn][2], acc[am][bn][3]);
            }
        __syncthreads();
        const int bq = m0g >> 11;
        const int t0 = m0g & 2047;
        const int nr = tid >> 1;            // 0..127 (n row)
        const int tc = (tid & 1) * 64;      // t chunk half
        unsigned short* vp = C + (size_t)(bq * 512 + n0 + nr) * T_SEQ + t0 + tc;
        #pragma unroll
        for (int j = 0; j < 8; ++j)
            *reinterpret_cast<int4*>(vp + j * 8) =
                *reinterpret_cast<const int4*>(&Tl[nr][tc + j * 8]);
    }
}

// ---------------------------------------------------------------------------
// Fused output projections (big path): clone of the proj_fused BK=32
// 3-buffer counted-vmcnt skeleton. A = AO bf16 (ws), W = Wo bf16 (converted
// into dead K1 region by wo_bf16). fp32 C epilogue in two 64-row passes
// through a 33.8 KB LDS overlay, 128B/thread coalesced stores. 3 blocks/CU.
// Grid 512 = 2 z x 64 mt x 4 nh, bijective XCD swizzle (q=64).
// ---------------------------------------------------------------------------
__global__ __launch_bounds__(256, 3)
void out_fused(const unsigned short* __restrict__ AO1,
               const unsigned short* __restrict__ Wb1, float* __restrict__ C1,
               const unsigned short* __restrict__ AO2,
               const unsigned short* __restrict__ Wb2, float* __restrict__ C2)
{
    __shared__ __align__(16) char smem[49152];
    short (*Al)[128][32] = reinterpret_cast<short (*)[128][32]>(smem);           // 24 KB
    short (*Wl)[128][32] = reinterpret_cast<short (*)[128][32]>(smem + 24576);   // 24 KB

    const int o   = blockIdx.x;              // 512
    const int wg  = (o & 7) * 64 + (o >> 3); // bijective, 512 % 8 == 0
    const int z   = wg >> 8;
    const int idx = wg & 255;
    const int nh  = idx & 3;
    const int mt  = idx >> 2;

    const unsigned short* A = z ? AO2 : AO1;
    const unsigned short* W = z ? Wb2 : Wb1;
    float* C = z ? C2 : C1;

    const int tid  = threadIdx.x;
    const int w    = tid >> 6;
    const int wr   = w >> 1;
    const int wc   = w & 1;
    const int lane = tid & 63;
    const int nl   = lane & 15;
    const int quad = lane >> 4;
    const int rof  = lane >> 2;
    const int cg   = (lane & 3) ^ ((lane >> 3) & 3);

    const int m0g = mt * 128;
    const int n0  = nh * 128;

    const unsigned short* srcA0 = A + (size_t)(m0g + w * 32 + rof) * 512 + cg * 8;
    const unsigned short* srcA1 = srcA0 + (size_t)16 * 512;
    const unsigned short* srcW0 = W + (size_t)(n0 + w * 32 + rof) * 512 + cg * 8;
    const unsigned short* srcW1 = srcW0 + (size_t)16 * 512;

    f32x4 acc[4][4] = {};

    auto stage = [&](int it, int buf) {
        const int k0 = it * 32;
        gload_lds16(srcA0 + k0, &Al[buf][w * 32][0]);
        gload_lds16(srcA1 + k0, &Al[buf][w * 32 + 16][0]);
        gload_lds16(srcW0 + k0, &Wl[buf][w * 32][0]);
        gload_lds16(srcW1 + k0, &Wl[buf][w * 32 + 16][0]);
    };

    stage(0, 0);
    stage(1, 1);
    asm volatile("s_waitcnt vmcnt(4)" ::: "memory");
    raw_barrier();

    const int key = (nl >> 1) & 3;
    int bcur = 0, bpre = 2;
    for (int it = 0; it < 16; ++it) {
        if (it < 14) stage(it + 2, bpre);
        bf16x8 a[4], bb[4];
        #pragma unroll
        for (int am = 0; am < 4; ++am)
            a[am] = *reinterpret_cast<const bf16x8*>(
                &Al[bcur][wr * 64 + am * 16 + nl][(quad ^ key) * 8]);
        #pragma unroll
        for (int bn = 0; bn < 4; ++bn)
            bb[bn] = *reinterpret_cast<const bf16x8*>(
                &Wl[bcur][wc * 64 + bn * 16 + nl][(quad ^ key) * 8]);
        #pragma unroll
        for (int am = 0; am < 4; ++am)
            #pragma unroll
            for (int bn = 0; bn < 4; ++bn)
                acc[am][bn] = __builtin_amdgcn_mfma_f32_16x16x32_bf16(
                    a[am], bb[bn], acc[am][bn], 0, 0, 0);
        if (it < 14)       asm volatile("s_waitcnt vmcnt(4)" ::: "memory");
        else if (it == 14) asm volatile("s_waitcnt vmcnt(0)" ::: "memory");
        raw_barrier();
        bcur = (bcur == 2) ? 0 : bcur + 1;
        bpre = (bpre == 2) ? 0 : bpre + 1;
    }

    // ---- fp32 epilogue: two 64-row passes through 33.8 KB LDS overlay ----
    float (*Cl)[132] = reinterpret_cast<float (*)[132]>(smem);
    const int lr = tid >> 2;            // 0..63
    const int fc = (tid & 3) * 32;      // 32-float chunk
    // pass 0: rows 0..63 (waves wr==0)
    if (wr == 0) {
        #pragma unroll
        for (int am = 0; am < 4; ++am)
            #pragma unroll
            for (int bn = 0; bn < 4; ++bn)
                #pragma unroll
                for (int r = 0; r < 4; ++r)
                    Cl[am * 16 + quad * 4 + r][wc * 64 + bn * 16 + nl] =
                        acc[am][bn][r];
    }
    __syncthreads();
    {
        float* cp = C + (size_t)(m0g + lr) * 512 + n0 + fc;
        #pragma unroll
        for (int j = 0; j < 8; ++j)
            *reinterpret_cast<float4*>(cp + j * 4) =
                *reinterpret_cast<const float4*>(&Cl[lr][fc + j * 4]);
    }
    __syncthreads();
    // pass 1: rows 64..127 (waves wr==1)
    if (wr == 1) {
        #pragma unroll
        for (int am = 0; am < 4; ++am)
            #pragma unroll
            for (int bn = 0; bn < 4; ++bn)
                #pragma unroll
                for (int r = 0; r < 4; ++r)
                    Cl[am * 16 + quad * 4 + r][wc * 64 + bn * 16 + nl] =
                        acc[am][bn][r];
    }
    __syncthreads();
    {
        float* cp = C + (size_t)(m0g + 64 + lr) * 512 + n0 + fc;
        #pragma unroll
        for (int j = 0; j < 8; ++j)
            *reinterpret_cast<float4*>(cp + j * 4) =
                *reinterpret_cast<const float4*>(&Cl[lr][fc + j * 4]);
    }
}

// ---------------------------------------------------------------------------
// Fallback output projection (small-ws path only).
// ---------------------------------------------------------------------------
__global__ __launch_bounds__(256)
void out_proj(const unsigned short* __restrict__ AO1, const float* __restrict__ Wo1,
              float* __restrict__ C1,
              const unsigned short* __restrict__ AO2, const float* __restrict__ Wo2,
              float* __restrict__ C2, int zbase)
{
    const int z = zbase + blockIdx.z;
    const unsigned short* A = z ? AO2 : AO1;
    const float* W = z ? Wo2 : Wo1;
    float* C = z ? C2 : C1;

    MF_SETUP
    const unsigned short* ap = A + (size_t)(m0 + arow) * 512 + acol;
    const float* wp = W + (size_t)(n0 + arow) * 512 + acol;
    int4 ai[2];
    float4 wv[4];
    ai[0] = *reinterpret_cast<const int4*>(ap);
    ai[1] = *reinterpret_cast<const int4*>(ap + 8);
    #pragma unroll
    for (int j = 0; j < 4; ++j)
        wv[j] = *reinterpret_cast<const float4*>(wp + 4 * j);
    for (int it = 0; it < 8; ++it) {
        __syncthreads();
        *reinterpret_cast<int4*>(&Asm[arow][acol])     = ai[0];
        *reinterpret_cast<int4*>(&Asm[arow][acol + 8]) = ai[1];
        MF_WRITE_W
        __syncthreads();
        if (it < 7) {
            const unsigned short* apn = ap + (it + 1) * 64;
            const float* wpn = wp + (it + 1) * 64;
            ai[0] = *reinterpret_cast<const int4*>(apn);
            ai[1] = *reinterpret_cast<const int4*>(apn + 8);
            #pragma unroll
            for (int j = 0; j < 4; ++j)
                wv[j] = *reinterpret_cast<const float4*>(wpn + 4 * j);
        }
        MF_MMA_LOOP
    }
    #pragma unroll
    for (int c = 0; c < 4; ++c)
        #pragma unroll
        for (int r = 0; r < 4; ++r)
            C[(size_t)(m0 + w4 * 16 + quad * 4 + r) * 512 + n0 + c * 16 + nl] =
                acc[c][r];
}

// ---------------------------------------------------------------------------
// MFMA flash attention, both directions in one dispatch (blockIdx.y >> 5).
// Block = 8 waves / 512 threads = one (dir,b,h,128-row q-tile); wave owns 16
// q rows. NEW: K/V TRIPLE-buffered with counted vmcnt (issue tile kt+2 at
// top, wait vmcnt(2) at a RAW barrier -> each DMA gets 2 iterations of
// latency cover; never drains to 0 in the main loop). LDS 64 KB exactly
// (3x8KB K + 3x8KB V + 16KB Pl) -> 2 blocks/CU (= measured residency of the
// previous 48 KB version, so no real occupancy loss). FIXED-MAX softmax
// (log2-domain); mask bias rides the QK MFMA C-input; l-reduce once at
// epilogue; s_setprio(1) wraps PV cluster. AO aliases Q (block-local RAW).
// ---------------------------------------------------------------------------
__global__ __launch_bounds__(512)
void attn_mfma(const unsigned short* Q1x, const unsigned short* __restrict__ K1x,
               const unsigned short* __restrict__ V1x, const float* __restrict__ b1x,
               unsigned short* AO1x,
               const unsigned short* Q2x, const unsigned short* __restrict__ K2x,
               const unsigned short* __restrict__ V2x, const float* __restrict__ b2x,
               unsigned short* AO2x)
{
    __shared__ short Kl[3][64][64];   // [buf][kv_row][d] (swizzled 16B slots)
    __shared__ short Vl[3][64][64];   // [buf][d_row][kv] (swizzled 16B slots)
    __shared__ short Pl[8][16][64];   // pitch 64 + slot-XOR; total LDS = 64 KB

    const int dir = blockIdx.y >> 5;
    const unsigned short* Q  = dir ? Q2x : Q1x;
    const unsigned short* K  = dir ? K2x : K1x;
    const unsigned short* Vt = dir ? V2x : V1x;
    const float* biasD       = dir ? b2x : b1x;
    unsigned short* AO       = dir ? AO2x : AO1x;

    const int tid  = threadIdx.x;
    const int w    = tid >> 6;              // 0..7
    const int lane = tid & 63;
    const int nl   = lane & 15;
    const int quad = lane >> 4;
    const int qt = blockIdx.x;              // 0..15 (128-row q-tiles)
    const int bh = blockIdx.y & 31;         // 0..31
    const int b = bh >> 3, h = bh & 7;
    const size_t tb = (size_t)b * (T_SEQ * 512);
    const float* biasB = biasD + b * T_SEQ;

    const int r8 = lane >> 3;
    const int cg = (lane & 7) ^ r8;
    const int sr = w * 8;                   // this wave's staging row base

    // each wave stages 8 K-rows + 8 V-rows per tile = 2 gloads/wave/stage
    auto stageKV = [&](int t, int buf) {
        gload_lds16(K + tb + (size_t)(t * 64 + sr + r8) * 512 + h * 64 + cg * 8,
                    &Kl[buf][sr][0]);
        gload_lds16(Vt + (size_t)(b * 512 + h * 64 + sr + r8) * T_SEQ +
                        (size_t)t * 64 + cg * 8,
                    &Vl[buf][sr][0]);
    };

    // Q B-frags (n=lane&15 => q row, k=quad*8+j)
    const unsigned short* qp = Q + tb + (size_t)(qt * 128 + w * 16 + nl) * 512 + h * 64 + quad * 8;
    const bf16x8 qb0 = ldg8(qp);
    const bf16x8 qb1 = ldg8(qp + 32);

    float l_run = 0.0f;   // lane-local partial (this lane's kv slots only)
    f32x4 o[4] = {};   // O^T: o[sd] holds d = sd*16+quad*4+r (row), q = nl (col)

    // prologue: tiles 0,1 in flight; wait for tile 0 only (2 loads/stage)
    stageKV(0, 0);
    stageKV(1, 1);
    asm volatile("s_waitcnt vmcnt(2)" ::: "memory");
    raw_barrier();

    const int swz = nl & 7;

    int bcur = 0, bpre = 2;
    for (int kt = 0; kt < 32; ++kt) {
        if (kt < 30) stageKV(kt + 2, bpre);
        short (*Kb)[64] = Kl[bcur];
        short (*Vb)[64] = Vl[bcur];

        // scores S^T[kv][q] (log2 domain); mask bias enters as MFMA C-input
        float p[4][4];
        #pragma unroll
        for (int s = 0; s < 4; ++s) {
            const bf16x8 k0 = *reinterpret_cast<const bf16x8*>(&Kb[s * 16 + nl][(quad ^ swz) * 8]);
            const bf16x8 k1 = *reinterpret_cast<const bf16x8*>(&Kb[s * 16 + nl][((4 + quad) ^ swz) * 8]);
            const float4 bb = *reinterpret_cast<const float4*>(
                &biasB[kt * 64 + s * 16 + quad * 4]);
            f32x4 z = {bb.x, bb.y, bb.z, bb.w};
            z = __builtin_amdgcn_mfma_f32_16x16x32_bf16(k0, qb0, z, 0, 0, 0);
            z = __builtin_amdgcn_mfma_f32_16x16x32_bf16(k1, qb1, z, 0, 0, 0);
            p[s][0] = fexp2(z[0]);
            p[s][1] = fexp2(z[1]);
            p[s][2] = fexp2(z[2]);
            p[s][3] = fexp2(z[3]);
            l_run += p[s][0] + p[s][1] + p[s][2] + p[s][3];
        }

        // P -> LDS [q][kv], pitch 64 with 16B-slot XOR (key = nl&7).
        #pragma unroll
        for (int s = 0; s < 4; ++s) {
            int2 pk;
            pk.x = pack2bf(p[s][0], p[s][1]);
            pk.y = pack2bf(p[s][2], p[s][3]);
            const int slot = (2 * s + (quad >> 1)) ^ swz;
            *reinterpret_cast<int2*>(&Pl[w][nl][slot * 8 + (quad & 1) * 4]) = pk;
        }

        // O^T += V^T · P^T (pa read back with the same slot-XOR)
        const bf16x8 pa0 = *reinterpret_cast<const bf16x8*>(&Pl[w][nl][(quad ^ swz) * 8]);
        const bf16x8 pa1 = *reinterpret_cast<const bf16x8*>(&Pl[w][nl][((4 + quad) ^ swz) * 8]);
        __builtin_amdgcn_s_setprio(1);
        #pragma unroll
        for (int sd = 0; sd < 4; ++sd) {
            const bf16x8 v0 = *reinterpret_cast<const bf16x8*>(&Vb[sd * 16 + nl][(quad ^ swz) * 8]);
            const bf16x8 v1 = *reinterpret_cast<const bf16x8*>(&Vb[sd * 16 + nl][((4 + quad) ^ swz) * 8]);
            o[sd] = __builtin_amdgcn_mfma_f32_16x16x32_bf16(v0, pa0, o[sd], 0, 0, 0);
            o[sd] = __builtin_amdgcn_mfma_f32_16x16x32_bf16(v1, pa1, o[sd], 0, 0, 0);
        }
        __builtin_amdgcn_s_setprio(0);

        // counted wait: tile kt+1 landed, kt+2 still in flight
        if (kt < 30)       asm volatile("s_waitcnt vmcnt(2)" ::: "memory");
        else if (kt == 30) asm volatile("s_waitcnt vmcnt(0)" ::: "memory");
        if (kt < 31) raw_barrier();
        bcur = (bcur == 2) ? 0 : bcur + 1;
        bpre = (bpre == 2) ? 0 : bpre + 1;
    }

    // epilogue: reduce l across the 4 kv-quadrant lanes ONCE, then store
    l_run += __shfl_xor(l_run, 16);
    l_run += __shfl_xor(l_run, 32);
    const float inv = 1.0f / l_run;
    unsigned short* ob = AO + tb + (size_t)(qt * 128 + w * 16 + nl) * 512 + h * 64 + quad * 4;
    #pragma unroll
    for (int sd = 0; sd < 4; ++sd) {
        ushort4 o4;
        o4.x = f2b(o[sd][0] * inv);
        o4.y = f2b(o[sd][1] * inv);
        o4.z = f2b(o[sd][2] * inv);
        o4.w = f2b(o[sd][3] * inv);
        *reinterpret_cast<ushort4*>(ob + sd * 16) = o4;
    }
}

extern "C" void kernel_launch(void* const* d_in, const int* in_sizes, int n_in,
                              void* d_out, int out_size, void* d_ws, size_t ws_size,
                              hipStream_t stream) {
    const float* skel = (const float*)d_in[0];
    const float* sens = (const float*)d_in[1];
    const int* mask_skel = (const int*)d_in[2];
    const int* mask_sens = (const int*)d_in[3];
    const float* Wq_s2e = (const float*)d_in[4];
    const float* Wk_e   = (const float*)d_in[5];
    const float* Wv_e   = (const float*)d_in[6];
    const float* Wq_e2s = (const float*)d_in[7];
    const float* Wk_s   = (const float*)d_in[8];
    const float* Wv_s   = (const float*)d_in[9];
    const float* Wo_s   = (const float*)d_in[10];
    const float* Wo_e   = (const float*)d_in[11];
    float* out = (float*)d_out;   // fp32: [e2s (4M)][s2e (4M)]

    unsigned short* Q1 = (unsigned short*)d_ws;    // dir0 Q / AO (aliased)
    unsigned short* K1 = Q1 + N_TOK;
    unsigned short* V1 = K1 + N_TOK;               // Vt

    const bool big = ws_size >= (size_t)6 * N_TOK * sizeof(unsigned short);

    if (big) {
        unsigned short* Q2 = V1 + N_TOK;
        unsigned short* K2 = Q2 + N_TOK;
        unsigned short* V2 = K2 + N_TOK;
        // bf16+bias scratch lives in d_out (dead until out_fused, stream order)
        unsigned short* SC  = (unsigned short*)d_out;
        unsigned short* skb = SC;
        unsigned short* snb = SC + N_TOK;
        unsigned short* wb  = SC + 2 * (size_t)N_TOK;
        float* biasS = (float*)(SC + 2 * (size_t)N_TOK + 6 * W_ELEM);
        float* bias0 = biasS;                 // dir0 <- mask_sens
        float* bias1 = biasS + 4 * T_SEQ;     // dir1 <- mask_skel
        prep_bias<<<dim3(8), 256, 0, stream>>>(mask_sens, mask_skel, biasS);
        to_bf16<<<dim3(4864), 256, 0, stream>>>(
            skel, sens, Wq_s2e, Wk_e, Wv_e, Wq_e2s, Wk_s, Wv_s, SC);
        // dir0 = s2e (out slot 1), dir1 = e2s (out slot 0)
        proj_fused<<<dim3(1536), 256, 0, stream>>>(
            skb, snb, wb, Q1, K1, V1, Q2, K2, V2);
        attn_mfma<<<dim3(16, 64), 512, 0, stream>>>(
            Q1, K1, V1, bias0, Q1,
            Q2, K2, V2, bias1, Q2);
        // Wo -> bf16 into dead K1 region, then fused output projections
        wo_bf16<<<dim3(256), 256, 0, stream>>>(Wo_e, Wo_s, K1);
        out_fused<<<dim3(512), 256, 0, stream>>>(
            Q1, K1, out + N_TOK, Q2, K1 + W_ELEM, out);
    } else {
        // sequential fallback: reuse the 3-buffer workspace per direction.
        // bias scratch in the e2s half of out (overwritten by the LAST
        // out_proj, after its final use).
        float* bias0 = out;                   // dir0 <- mask_sens
        float* bias1 = out + 8192;            // dir1 <- mask_skel
        prep_bias<<<dim3(8), 256, 0, stream>>>(mask_sens, mask_skel, bias0);
        proj_all<<<dim3(8, 128, 3), 256, 0, stream>>>(
            skel, sens, Wq_s2e, Wk_e, Wv_e, Wq_e2s, Wk_s, Wv_s,
            Q1, K1, V1, Q1, K1, V1, 0);
        attn_mfma<<<dim3(16, 32), 512, 0, stream>>>(
            Q1, K1, V1, bias0, Q1, Q1, K1, V1, bias0, Q1);
        out_proj<<<dim3(8, 128, 1), 256, 0, stream>>>(
            Q1, Wo_e, out + N_TOK, Q1, Wo_s, out, 0);
        proj_all<<<dim3(8, 128, 3), 256, 0, stream>>>(
            skel, sens, Wq_s2e, Wk_e, Wv_e, Wq_e2s, Wk_s, Wv_s,
            Q1, K1, V1, Q1, K1, V1, 3);
        attn_mfma<<<dim3(16, 32), 512, 0, stream>>>(
            Q1, K1, V1, bias1, Q1, Q1, K1, V1, bias1, Q1);
        out_proj<<<dim3(8, 128, 1), 256, 0, stream>>>(
            Q1, Wo_s, out, Q1, Wo_s, out, 1);
    }
}

// Round 15
// 264.441 us; speedup vs baseline: 1.6371x; 1.0348x over previous
//
#include <hip/hip_runtime.h>
#include <hip/hip_bf16.h>

// Problem constants: B=4, T=2048, D=512, H=8, DK=64
#define T_SEQ 2048
#define N_TOK 4194304   // 4 * 2048 * 512 elements per [B,T,D] tensor
#define W_ELEM 262144   // 512*512

// Inputs: FLOAT32. Output: FLOAT32, (e2s, s2e) concat.
// ws (fused path, 48 MB): Q1,K1 [B,T,512] bf16; Vt1 [B,512,T] bf16; Q2,K2,Vt2.
// AO aliases Q per direction. After attn, K1 is reused for bf16 Wo scratch.
// Fallback (<48 MB ws): 24 MB, sequential.
// Big path: d_out doubles as scratch (skel,sens bf16; 6 proj W bf16; bias
// floats) until out_fused runs (strict stream order).

typedef float f32x4  __attribute__((ext_vector_type(4)));
typedef short bf16x8 __attribute__((ext_vector_type(8)));

// 1.5/sqrt(64) * log2(e): attention logits are produced in log2 domain so
// softmax uses bare v_exp_f32 (exp2) with no per-element multiply.
#define SCALE_Q 0.27050532f

__device__ __forceinline__ unsigned short f2b(float f) {
    __hip_bfloat16 h = __float2bfloat16(f);
    return *reinterpret_cast<unsigned short*>(&h);
}

__device__ __forceinline__ int pack2bf(float lo, float hi) {
    return ((int)f2b(hi) << 16) | (int)f2b(lo);
}

__device__ __forceinline__ bf16x8 ldg8(const unsigned short* p) {
    union { int4 i; bf16x8 b; } u;
    u.i = *reinterpret_cast<const int4*>(p);
    return u.b;
}

__device__ __forceinline__ float fexp2(float x) {
#if __has_builtin(__builtin_amdgcn_exp2f)
    return __builtin_amdgcn_exp2f(x);
#else
    return exp2f(x);
#endif
}

// async global->LDS DMA, 16B per lane; LDS dest = wave-uniform base + lane*16
typedef unsigned int u32_g __attribute__((address_space(1)));
typedef unsigned int u32_l __attribute__((address_space(3)));
__device__ __forceinline__ void gload_lds16(const void* g, void* l) {
    __builtin_amdgcn_global_load_lds((const u32_g*)g, (u32_l*)l, 16, 0, 0);
}

// raw barrier (no compiler-inserted vmcnt(0) drain) with scheduling fences
__device__ __forceinline__ void raw_barrier() {
    __builtin_amdgcn_sched_barrier(0);
    __builtin_amdgcn_s_barrier();
    __builtin_amdgcn_sched_barrier(0);
}

// ---------------------------------------------------------------------------
// mask -> additive float bias precompute: dst = [2][B][T_SEQ] floats (64 KB).
// dir0 <- mask_sens, dir1 <- mask_skel. Grid 8. (fallback path only)
// ---------------------------------------------------------------------------
__global__ __launch_bounds__(256)
void prep_bias(const int* __restrict__ ms, const int* __restrict__ mk,
               float* __restrict__ dst)
{
    const int i = (blockIdx.x * 256 + threadIdx.x) * 8;   // 16384 total
    const int* m = (i >> 13) ? mk : ms;
    const int rem = i & 8191;
    const int4 a = *reinterpret_cast<const int4*>(&m[rem]);
    const int4 b = *reinterpret_cast<const int4*>(&m[rem + 4]);
    float4 f0, f1;
    f0.x = a.x ? 0.0f : -3e38f; f0.y = a.y ? 0.0f : -3e38f;
    f0.z = a.z ? 0.0f : -3e38f; f0.w = a.w ? 0.0f : -3e38f;
    f1.x = b.x ? 0.0f : -3e38f; f1.y = b.y ? 0.0f : -3e38f;
    f1.z = b.z ? 0.0f : -3e38f; f1.w = b.w ? 0.0f : -3e38f;
    *reinterpret_cast<float4*>(&dst[i])     = f0;
    *reinterpret_cast<float4*>(&dst[i + 4]) = f1;
}

// ---------------------------------------------------------------------------
// fp32 -> bf16 pre-conversion + mask bias, exact 1D grid (4872 blocks):
// [0,2048) skel, [2048,4096) sens, [4096,4864) 6 x 128 proj weights,
// [4864,4872) mask->bias floats (dir0 <- mask_sens, dir1 <- mask_skel).
// ---------------------------------------------------------------------------
__global__ __launch_bounds__(256)
void to_bf16(const float* __restrict__ s0, const float* __restrict__ s1,
             const float* __restrict__ w0, const float* __restrict__ w1,
             const float* __restrict__ w2, const float* __restrict__ w3,
             const float* __restrict__ w4, const float* __restrict__ w5,
             const int* __restrict__ ms, const int* __restrict__ mk,
             unsigned short* __restrict__ dst, float* __restrict__ biasS)
{
    const int bid = blockIdx.x;
    if (bid >= 4864) {
        const int i = ((bid - 4864) * 256 + threadIdx.x) * 8;
        const int* m = (i >> 13) ? mk : ms;
        const int rem = i & 8191;
        const int4 a = *reinterpret_cast<const int4*>(&m[rem]);
        const int4 b = *reinterpret_cast<const int4*>(&m[rem + 4]);
        float4 f0, f1;
        f0.x = a.x ? 0.0f : -3e38f; f0.y = a.y ? 0.0f : -3e38f;
        f0.z = a.z ? 0.0f : -3e38f; f0.w = a.w ? 0.0f : -3e38f;
        f1.x = b.x ? 0.0f : -3e38f; f1.y = b.y ? 0.0f : -3e38f;
        f1.z = b.z ? 0.0f : -3e38f; f1.w = b.w ? 0.0f : -3e38f;
        *reinterpret_cast<float4*>(&biasS[i])     = f0;
        *reinterpret_cast<float4*>(&biasS[i + 4]) = f1;
        return;
    }
    int y, x;
    if (bid < 4096) { y = bid >> 11; x = bid & 2047; }
    else { const int t = bid - 4096; y = 2 + (t >> 7); x = t & 127; }
    const float* src;
    size_t off;
    switch (y) {
        case 0: src = s0; off = 0;      break;
        case 1: src = s1; off = N_TOK;  break;
        case 2: src = w0; off = 2 * (size_t)N_TOK;              break;
        case 3: src = w1; off = 2 * (size_t)N_TOK + 1 * W_ELEM; break;
        case 4: src = w2; off = 2 * (size_t)N_TOK + 2 * W_ELEM; break;
        case 5: src = w3; off = 2 * (size_t)N_TOK + 3 * W_ELEM; break;
        case 6: src = w4; off = 2 * (size_t)N_TOK + 4 * W_ELEM; break;
        default: src = w5; off = 2 * (size_t)N_TOK + 5 * W_ELEM; break;
    }
    const int idx = (x * 256 + threadIdx.x) * 8;
    const float4 a = *reinterpret_cast<const float4*>(src + idx);
    const float4 b = *reinterpret_cast<const float4*>(src + idx + 4);
    int4 o;
    o.x = pack2bf(a.x, a.y); o.y = pack2bf(a.z, a.w);
    o.z = pack2bf(b.x, b.y); o.w = pack2bf(b.z, b.w);
    *reinterpret_cast<int4*>(dst + off + idx) = o;
}

// ---------------------------------------------------------------------------
// Wo fp32 -> bf16 (runs after attn; dst = dead K1 ws region, 1 MB).
// ---------------------------------------------------------------------------
__global__ __launch_bounds__(256)
void wo_bf16(const float* __restrict__ we, const float* __restrict__ wsrc,
             unsigned short* __restrict__ dst)
{
    const int i = (blockIdx.x * 256 + threadIdx.x) * 8;   // 0..524280
    const float* src = (i >= W_ELEM) ? wsrc : we;
    const int rem = i & (W_ELEM - 1);
    const float4 a = *reinterpret_cast<const float4*>(src + rem);
    const float4 b = *reinterpret_cast<const float4*>(src + rem + 4);
    int4 o;
    o.x = pack2bf(a.x, a.y); o.y = pack2bf(a.z, a.w);
    o.z = pack2bf(b.x, b.y); o.w = pack2bf(b.z, b.w);
    *reinterpret_cast<int4*>(dst + i) = o;
}

// ---------------------------------------------------------------------------
// Shared MFMA-GEMM tile machinery (fallback proj + fallback out_proj).
// ---------------------------------------------------------------------------
#define MF_SETUP                                                               \
    __shared__ short Asm[64][72];                                              \
    __shared__ short Wsm[64][72];                                              \
    const int tid  = threadIdx.x;                                              \
    const int lane = tid & 63;                                                 \
    const int w4   = tid >> 6;                                                 \
    const int nl   = lane & 15;                                                \
    const int quad = lane >> 4;                                                \
    const int n0 = blockIdx.x * 64;                                            \
    const int m0 = blockIdx.y * 64;                                            \
    const int arow = tid >> 2;                                                 \
    const int acol = (tid & 3) * 16;                                           \
    f32x4 acc[4] = {};

#define MF_WRITE_W                                                             \
    {                                                                          \
        int4 x;                                                                \
        x.x = pack2bf(wv[0].x, wv[0].y); x.y = pack2bf(wv[0].z, wv[0].w);      \
        x.z = pack2bf(wv[1].x, wv[1].y); x.w = pack2bf(wv[1].z, wv[1].w);      \
        *reinterpret_cast<int4*>(&Wsm[arow][acol]) = x;                        \
        x.x = pack2bf(wv[2].x, wv[2].y); x.y = pack2bf(wv[2].z, wv[2].w);      \
        x.z = pack2bf(wv[3].x, wv[3].y); x.w = pack2bf(wv[3].z, wv[3].w);      \
        *reinterpret_cast<int4*>(&Wsm[arow][acol + 8]) = x;                    \
    }

#define MF_MMA_LOOP                                                            \
    _Pragma("unroll")                                                          \
    for (int kc = 0; kc < 2; ++kc) {                                           \
        const bf16x8 a = *reinterpret_cast<const bf16x8*>(                     \
            &Asm[w4 * 16 + nl][kc * 32 + quad * 8]);                           \
        _Pragma("unroll")                                                      \
        for (int c = 0; c < 4; ++c) {                                          \
            const bf16x8 bf = *reinterpret_cast<const bf16x8*>(                \
                &Wsm[c * 16 + nl][kc * 32 + quad * 8]);                        \
            acc[c] = __builtin_amdgcn_mfma_f32_16x16x32_bf16(a, bf, acc[c],    \
                                                             0, 0, 0);         \
        }                                                                      \
    }

#define MF_CWRITE_PROJ                                                         \
    if (!trans) {                                                              \
        _Pragma("unroll")                                                      \
        for (int c = 0; c < 4; ++c)                                            \
            _Pragma("unroll")                                                  \
            for (int r = 0; r < 4; ++r)                                        \
                C[(size_t)(m0 + w4 * 16 + quad * 4 + r) * 512 + n0 + c * 16 + nl] = \
                    f2b(acc[c][r] * alpha);                                    \
    } else {                                                                   \
        const int b  = m0 >> 11;                                               \
        const int t0 = (m0 & 2047) + w4 * 16 + quad * 4;                       \
        _Pragma("unroll")                                                      \
        for (int c = 0; c < 4; ++c) {                                          \
            const int n = n0 + c * 16 + nl;                                    \
            ushort4 o;                                                         \
            o.x = f2b(acc[c][0]);                                              \
            o.y = f2b(acc[c][1]);                                              \
            o.z = f2b(acc[c][2]);                                              \
            o.w = f2b(acc[c][3]);                                              \
            *reinterpret_cast<ushort4*>(C + (size_t)(b * 512 + n) * T_SEQ + t0) = o; \
        }                                                                      \
    }

// ---------------------------------------------------------------------------
// fp32-input projections (fallback path only).
// ---------------------------------------------------------------------------
__global__ __launch_bounds__(256)
void proj_all(const float* __restrict__ skel, const float* __restrict__ sens,
              const float* __restrict__ Wq1, const float* __restrict__ Wk1,
              const float* __restrict__ Wv1, const float* __restrict__ Wq2,
              const float* __restrict__ Wk2, const float* __restrict__ Wv2,
              unsigned short* __restrict__ Q1, unsigned short* __restrict__ K1,
              unsigned short* __restrict__ Vt1, unsigned short* __restrict__ Q2,
              unsigned short* __restrict__ K2, unsigned short* __restrict__ Vt2,
              int zbase)
{
    const int z = zbase + blockIdx.z;
    const float* A; const float* W; unsigned short* C;
    float alpha = 1.0f; bool trans = false;
    switch (z) {
        case 0:  A = skel; W = Wq1; C = Q1; alpha = SCALE_Q; break;
        case 1:  A = sens; W = Wk1; C = K1; break;
        case 2:  A = sens; W = Wv1; C = Vt1; trans = true; break;
        case 3:  A = sens; W = Wq2; C = Q2; alpha = SCALE_Q; break;
        case 4:  A = skel; W = Wk2; C = K2; break;
        default: A = skel; W = Wv2; C = Vt2; trans = true; break;
    }

    MF_SETUP
    const float* ap = A + (size_t)(m0 + arow) * 512 + acol;
    const float* wp = W + (size_t)(n0 + arow) * 512 + acol;
    float4 av[4], wv[4];
    #pragma unroll
    for (int j = 0; j < 4; ++j) {
        av[j] = *reinterpret_cast<const float4*>(ap + 4 * j);
        wv[j] = *reinterpret_cast<const float4*>(wp + 4 * j);
    }
    for (int it = 0; it < 8; ++it) {
        __syncthreads();
        {
            int4 x;
            x.x = pack2bf(av[0].x, av[0].y); x.y = pack2bf(av[0].z, av[0].w);
            x.z = pack2bf(av[1].x, av[1].y); x.w = pack2bf(av[1].z, av[1].w);
            *reinterpret_cast<int4*>(&Asm[arow][acol]) = x;
            x.x = pack2bf(av[2].x, av[2].y); x.y = pack2bf(av[2].z, av[2].w);
            x.z = pack2bf(av[3].x, av[3].y); x.w = pack2bf(av[3].z, av[3].w);
            *reinterpret_cast<int4*>(&Asm[arow][acol + 8]) = x;
        }
        MF_WRITE_W
        __syncthreads();
        if (it < 7) {
            const float* apn = ap + (it + 1) * 64;
            const float* wpn = wp + (it + 1) * 64;
            #pragma unroll
            for (int j = 0; j < 4; ++j) {
                av[j] = *reinterpret_cast<const float4*>(apn + 4 * j);
                wv[j] = *reinterpret_cast<const float4*>(wpn + 4 * j);
            }
        }
        MF_MMA_LOOP
    }
    MF_CWRITE_PROJ
}

// ---------------------------------------------------------------------------
// Fused all-6-projection GEMM (big path), 128x128 tile, 4 waves (2x2), 4x4
// register blocking. BK=32 / 3-buffer counted-vmcnt pipeline (T3+T4).
// LDS 48 KB -> 3 blocks/CU. Plain C stores.
// ---------------------------------------------------------------------------
__global__ __launch_bounds__(256, 3)
void proj_fused(const unsigned short* __restrict__ skb,
                const unsigned short* __restrict__ snb,
                const unsigned short* __restrict__ wball,
                unsigned short* __restrict__ Q1, unsigned short* __restrict__ K1,
                unsigned short* __restrict__ Vt1, unsigned short* __restrict__ Q2,
                unsigned short* __restrict__ K2, unsigned short* __restrict__ Vt2)
{
    __shared__ __align__(16) char smem[49152];
    short (*Al)[128][32] = reinterpret_cast<short (*)[128][32]>(smem);           // 24 KB
    short (*Wl)[128][32] = reinterpret_cast<short (*)[128][32]>(smem + 24576);   // 24 KB

    // bijective XCD swizzle: nwg=1536, 8 XCDs, q=192
    const int o   = blockIdx.x;
    const int wg  = (o & 7) * 192 + (o >> 3);
    const int z   = wg >> 8;            // 0..5
    const int idx = wg & 255;
    const int nh  = idx & 3;            // n-tile, fastest: A-tile L2 reuse
    const int mt  = idx >> 2;           // 0..63

    const unsigned short* A = (z == 0 || z >= 4) ? skb : snb;
    const unsigned short* W = wball + (size_t)z * W_ELEM;
    unsigned short* C;
    switch (z) {
        case 0: C = Q1;  break;
        case 1: C = K1;  break;
        case 2: C = Vt1; break;
        case 3: C = Q2;  break;
        case 4: C = K2;  break;
        default: C = Vt2; break;
    }
    const bool trans = (z == 2 || z == 5);
    const float alpha = (z == 0 || z == 3) ? SCALE_Q : 1.0f;

    const int tid  = threadIdx.x;
    const int w    = tid >> 6;
    const int wr   = w >> 1;            // wave row (0..1)
    const int wc   = w & 1;             // wave col (0..1)
    const int lane = tid & 63;
    const int nl   = lane & 15;
    const int quad = lane >> 4;
    const int rof  = lane >> 2;                      // row offset in 16-row group
    const int cg   = (lane & 3) ^ ((lane >> 3) & 3); // inverse-swizzled chunk

    const int m0g = mt * 128;
    const int n0  = nh * 128;

    const unsigned short* srcA0 = A + (size_t)(m0g + w * 32 + rof) * 512 + cg * 8;
    const unsigned short* srcA1 = srcA0 + (size_t)16 * 512;
    const unsigned short* srcW0 = W + (size_t)(n0 + w * 32 + rof) * 512 + cg * 8;
    const unsigned short* srcW1 = srcW0 + (size_t)16 * 512;

    f32x4 acc[4][4] = {};

    auto stage = [&](int it, int buf) {
        const int k0 = it * 32;
        gload_lds16(srcA0 + k0, &Al[buf][w * 32][0]);
        gload_lds16(srcA1 + k0, &Al[buf][w * 32 + 16][0]);
        gload_lds16(srcW0 + k0, &Wl[buf][w * 32][0]);
        gload_lds16(srcW1 + k0, &Wl[buf][w * 32 + 16][0]);
    };

    stage(0, 0);
    stage(1, 1);
    asm volatile("s_waitcnt vmcnt(4)" ::: "memory");
    raw_barrier();

    const int key = (nl >> 1) & 3;
    int bcur = 0, bpre = 2;             // buffer for step i, and for step i+2
    for (int it = 0; it < 16; ++it) {
        if (it < 14) stage(it + 2, bpre);
        bf16x8 a[4], bb[4];
        #pragma unroll
        for (int am = 0; am < 4; ++am)
            a[am] = *reinterpret_cast<const bf16x8*>(
                &Al[bcur][wr * 64 + am * 16 + nl][(quad ^ key) * 8]);
        #pragma unroll
        for (int bn = 0; bn < 4; ++bn)
            bb[bn] = *reinterpret_cast<const bf16x8*>(
                &Wl[bcur][wc * 64 + bn * 16 + nl][(quad ^ key) * 8]);
        #pragma unroll
        for (int am = 0; am < 4; ++am)
            #pragma unroll
            for (int bn = 0; bn < 4; ++bn)
                acc[am][bn] = __builtin_amdgcn_mfma_f32_16x16x32_bf16(
                    a[am], bb[bn], acc[am][bn], 0, 0, 0);
        if (it < 14)       asm volatile("s_waitcnt vmcnt(4)" ::: "memory");
        else if (it == 14) asm volatile("s_waitcnt vmcnt(0)" ::: "memory");
        raw_barrier();
        bcur = (bcur == 2) ? 0 : bcur + 1;
        bpre = (bpre == 2) ? 0 : bpre + 1;
    }

    // ---- staged coalesced epilogue (all LDS dead; barrier passed) ----
    if (!trans) {
        short (*Cl)[136] = reinterpret_cast<short (*)[136]>(smem);  // 34.8 KB
        #pragma unroll
        for (int am = 0; am < 4; ++am)
            #pragma unroll
            for (int bn = 0; bn < 4; ++bn)
                #pragma unroll
                for (int r = 0; r < 4; ++r)
                    Cl[wr * 64 + am * 16 + quad * 4 + r][wc * 64 + bn * 16 + nl] =
                        (short)f2b(acc[am][bn][r] * alpha);
        __syncthreads();
        const int lr = tid >> 1;            // 0..127 (m row)
        const int ch = (tid & 1) * 64;      // short col half
        unsigned short* cp = C + (size_t)(m0g + lr) * 512 + n0 + ch;
        #pragma unroll
        for (int j = 0; j < 8; ++j)
            *reinterpret_cast<int4*>(cp + j * 8) =
                *reinterpret_cast<const int4*>(&Cl[lr][ch + j * 8]);
    } else {
        short (*Tl)[136] = reinterpret_cast<short (*)[136]>(smem);  // 34.8 KB
        #pragma unroll
        for (int am = 0; am < 4; ++am)
            #pragma unroll
            for (int bn = 0; bn < 4; ++bn) {
                int* dst = reinterpret_cast<int*>(
                    &Tl[wc * 64 + bn * 16 + nl][wr * 64 + am * 16 + quad * 4]);
                dst[0] = pack2bf(acc[am][bn][0], acc[am][bn][1]);
                dst[1] = pack2bf(acc[am][bn][2], acc[am][bn][3]);
            }
        __syncthreads();
        const int bq = m0g >> 11;
        const int t0 = m0g & 2047;
        const int nr = tid >> 1;            // 0..127 (n row)
        const int tc = (tid & 1) * 64;      // t chunk half
        unsigned short* vp = C + (size_t)(bq * 512 + n0 + nr) * T_SEQ + t0 + tc;
        #pragma unroll
        for (int j = 0; j < 8; ++j)
            *reinterpret_cast<int4*>(vp + j * 8) =
                *reinterpret_cast<const int4*>(&Tl[nr][tc + j * 8]);
    }
}

// ---------------------------------------------------------------------------
// Fused output projections (big path): proj_fused BK=32 3-buffer
// counted-vmcnt skeleton. A = AO bf16 (ws), W = Wo bf16 (dead K1 region).
// fp32 C epilogue in two 64-row passes through a 33.8 KB LDS overlay.
// Grid 512 = 2 z x 64 mt x 4 nh, bijective XCD swizzle (q=64). 3 blocks/CU.
// ---------------------------------------------------------------------------
__global__ __launch_bounds__(256, 3)
void out_fused(const unsigned short* __restrict__ AO1,
               const unsigned short* __restrict__ Wb1, float* __restrict__ C1,
               const unsigned short* __restrict__ AO2,
               const unsigned short* __restrict__ Wb2, float* __restrict__ C2)
{
    __shared__ __align__(16) char smem[49152];
    short (*Al)[128][32] = reinterpret_cast<short (*)[128][32]>(smem);           // 24 KB
    short (*Wl)[128][32] = reinterpret_cast<short (*)[128][32]>(smem + 24576);   // 24 KB

    const int o   = blockIdx.x;              // 512
    const int wg  = (o & 7) * 64 + (o >> 3); // bijective, 512 % 8 == 0
    const int z   = wg >> 8;
    const int idx = wg & 255;
    const int nh  = idx & 3;
    const int mt  = idx >> 2;

    const unsigned short* A = z ? AO2 : AO1;
    const unsigned short* W = z ? Wb2 : Wb1;
    float* C = z ? C2 : C1;

    const int tid  = threadIdx.x;
    const int w    = tid >> 6;
    const int wr   = w >> 1;
    const int wc   = w & 1;
    const int lane = tid & 63;
    const int nl   = lane & 15;
    const int quad = lane >> 4;
    const int rof  = lane >> 2;
    const int cg   = (lane & 3) ^ ((lane >> 3) & 3);

    const int m0g = mt * 128;
    const int n0  = nh * 128;

    const unsigned short* srcA0 = A + (size_t)(m0g + w * 32 + rof) * 512 + cg * 8;
    const unsigned short* srcA1 = srcA0 + (size_t)16 * 512;
    const unsigned short* srcW0 = W + (size_t)(n0 + w * 32 + rof) * 512 + cg * 8;
    const unsigned short* srcW1 = srcW0 + (size_t)16 * 512;

    f32x4 acc[4][4] = {};

    auto stage = [&](int it, int buf) {
        const int k0 = it * 32;
        gload_lds16(srcA0 + k0, &Al[buf][w * 32][0]);
        gload_lds16(srcA1 + k0, &Al[buf][w * 32 + 16][0]);
        gload_lds16(srcW0 + k0, &Wl[buf][w * 32][0]);
        gload_lds16(srcW1 + k0, &Wl[buf][w * 32 + 16][0]);
    };

    stage(0, 0);
    stage(1, 1);
    asm volatile("s_waitcnt vmcnt(4)" ::: "memory");
    raw_barrier();

    const int key = (nl >> 1) & 3;
    int bcur = 0, bpre = 2;
    for (int it = 0; it < 16; ++it) {
        if (it < 14) stage(it + 2, bpre);
        bf16x8 a[4], bb[4];
        #pragma unroll
        for (int am = 0; am < 4; ++am)
            a[am] = *reinterpret_cast<const bf16x8*>(
                &Al[bcur][wr * 64 + am * 16 + nl][(quad ^ key) * 8]);
        #pragma unroll
        for (int bn = 0; bn < 4; ++bn)
            bb[bn] = *reinterpret_cast<const bf16x8*>(
                &Wl[bcur][wc * 64 + bn * 16 + nl][(quad ^ key) * 8]);
        #pragma unroll
        for (int am = 0; am < 4; ++am)
            #pragma unroll
            for (int bn = 0; bn < 4; ++bn)
                acc[am][bn] = __builtin_amdgcn_mfma_f32_16x16x32_bf16(
                    a[am], bb[bn], acc[am][bn], 0, 0, 0);
        if (it < 14)       asm volatile("s_waitcnt vmcnt(4)" ::: "memory");
        else if (it == 14) asm volatile("s_waitcnt vmcnt(0)" ::: "memory");
        raw_barrier();
        bcur = (bcur == 2) ? 0 : bcur + 1;
        bpre = (bpre == 2) ? 0 : bpre + 1;
    }

    // ---- fp32 epilogue: two 64-row passes through 33.8 KB LDS overlay ----
    float (*Cl)[132] = reinterpret_cast<float (*)[132]>(smem);
    const int lr = tid >> 2;            // 0..63
    const int fc = (tid & 3) * 32;      // 32-float chunk
    if (wr == 0) {
        #pragma unroll
        for (int am = 0; am < 4; ++am)
            #pragma unroll
            for (int bn = 0; bn < 4; ++bn)
                #pragma unroll
                for (int r = 0; r < 4; ++r)
                    Cl[am * 16 + quad * 4 + r][wc * 64 + bn * 16 + nl] =
                        acc[am][bn][r];
    }
    __syncthreads();
    {
        float* cp = C + (size_t)(m0g + lr) * 512 + n0 + fc;
        #pragma unroll
        for (int j = 0; j < 8; ++j)
            *reinterpret_cast<float4*>(cp + j * 4) =
                *reinterpret_cast<const float4*>(&Cl[lr][fc + j * 4]);
    }
    __syncthreads();
    if (wr == 1) {
        #pragma unroll
        for (int am = 0; am < 4; ++am)
            #pragma unroll
            for (int bn = 0; bn < 4; ++bn)
                #pragma unroll
                for (int r = 0; r < 4; ++r)
                    Cl[am * 16 + quad * 4 + r][wc * 64 + bn * 16 + nl] =
                        acc[am][bn][r];
    }
    __syncthreads();
    {
        float* cp = C + (size_t)(m0g + 64 + lr) * 512 + n0 + fc;
        #pragma unroll
        for (int j = 0; j < 8; ++j)
            *reinterpret_cast<float4*>(cp + j * 4) =
                *reinterpret_cast<const float4*>(&Cl[lr][fc + j * 4]);
    }
}

// ---------------------------------------------------------------------------
// Fallback output projection (small-ws path only).
// ---------------------------------------------------------------------------
__global__ __launch_bounds__(256)
void out_proj(const unsigned short* __restrict__ AO1, const float* __restrict__ Wo1,
              float* __restrict__ C1,
              const unsigned short* __restrict__ AO2, const float* __restrict__ Wo2,
              float* __restrict__ C2, int zbase)
{
    const int z = zbase + blockIdx.z;
    const unsigned short* A = z ? AO2 : AO1;
    const float* W = z ? Wo2 : Wo1;
    float* C = z ? C2 : C1;

    MF_SETUP
    const unsigned short* ap = A + (size_t)(m0 + arow) * 512 + acol;
    const float* wp = W + (size_t)(n0 + arow) * 512 + acol;
    int4 ai[2];
    float4 wv[4];
    ai[0] = *reinterpret_cast<const int4*>(ap);
    ai[1] = *reinterpret_cast<const int4*>(ap + 8);
    #pragma unroll
    for (int j = 0; j < 4; ++j)
        wv[j] = *reinterpret_cast<const float4*>(wp + 4 * j);
    for (int it = 0; it < 8; ++it) {
        __syncthreads();
        *reinterpret_cast<int4*>(&Asm[arow][acol])     = ai[0];
        *reinterpret_cast<int4*>(&Asm[arow][acol + 8]) = ai[1];
        MF_WRITE_W
        __syncthreads();
        if (it < 7) {
            const unsigned short* apn = ap + (it + 1) * 64;
            const float* wpn = wp + (it + 1) * 64;
            ai[0] = *reinterpret_cast<const int4*>(apn);
            ai[1] = *reinterpret_cast<const int4*>(apn + 8);
            #pragma unroll
            for (int j = 0; j < 4; ++j)
                wv[j] = *reinterpret_cast<const float4*>(wpn + 4 * j);
        }
        MF_MMA_LOOP
    }
    #pragma unroll
    for (int c = 0; c < 4; ++c)
        #pragma unroll
        for (int r = 0; r < 4; ++r)
            C[(size_t)(m0 + w4 * 16 + quad * 4 + r) * 512 + n0 + c * 16 + nl] =
                acc[c][r];
}

// ---------------------------------------------------------------------------
// MFMA flash attention. 1-D grid with bijective XCD swizzle: all 16 q-tiles
// of one (dir,b,h) K/V panel land on ONE XCD (8 panels x 512 KB = 4 MB = one
// XCD L2) -> kills the 3x cross-XCD K/V re-fetch (R12: FETCH 139 MB vs 48 MB
// unique). Block = 8 waves / 512 threads = one 128-row q-tile; wave owns 16
// q rows. K/V double-buffered via global_load_lds (swizzled); LDS 48 KB.
// FIXED-MAX softmax (log2-domain); mask bias rides the QK MFMA C-input;
// l-reduce once at epilogue; s_setprio(1) wraps PV cluster. AO aliases Q.
// ---------------------------------------------------------------------------
__global__ __launch_bounds__(512)
void attn_mfma(const unsigned short* Q1x, const unsigned short* __restrict__ K1x,
               const unsigned short* __restrict__ V1x, const float* __restrict__ b1x,
               unsigned short* AO1x,
               const unsigned short* Q2x, const unsigned short* __restrict__ K2x,
               const unsigned short* __restrict__ V2x, const float* __restrict__ b2x,
               unsigned short* AO2x)
{
    __shared__ short Kl[2][64][64];   // [buf][kv_row][d] (swizzled 16B slots)
    __shared__ short Vl[2][64][64];   // [buf][d_row][kv] (swizzled 16B slots)
    __shared__ short Pl[8][16][64];   // pitch 64 + slot-XOR; total LDS = 48 KB

    // bijective XCD swizzle over the 1-D grid (nwg % 8 == 0)
    const int o   = blockIdx.x;
    const int qx  = gridDim.x >> 3;
    const int wg  = (o & 7) * qx + (o >> 3);
    const int qt  = wg & 15;               // q-tile: fastest -> same XCD panel
    const int bhd = wg >> 4;               // (dir,b,h) panel
    const int dir = bhd >> 5;
    const int bh  = bhd & 31;

    const unsigned short* Q  = dir ? Q2x : Q1x;
    const unsigned short* K  = dir ? K2x : K1x;
    const unsigned short* Vt = dir ? V2x : V1x;
    const float* biasD       = dir ? b2x : b1x;
    unsigned short* AO       = dir ? AO2x : AO1x;

    const int tid  = threadIdx.x;
    const int w    = tid >> 6;              // 0..7
    const int lane = tid & 63;
    const int nl   = lane & 15;
    const int quad = lane >> 4;
    const int b = bh >> 3, h = bh & 7;
    const size_t tb = (size_t)b * (T_SEQ * 512);
    const float* biasB = biasD + b * T_SEQ;

    const int r8 = lane >> 3;
    const int cg = (lane & 7) ^ r8;
    const int sr = w * 8;                   // this wave's staging row base

    // Q B-frags (n=lane&15 => q row, k=quad*8+j)
    const unsigned short* qp = Q + tb + (size_t)(qt * 128 + w * 16 + nl) * 512 + h * 64 + quad * 8;
    const bf16x8 qb0 = ldg8(qp);
    const bf16x8 qb1 = ldg8(qp + 32);

    float l_run = 0.0f;   // lane-local partial (this lane's kv slots only)
    f32x4 oacc[4] = {};   // O^T: oacc[sd] holds d = sd*16+quad*4+r, q = nl

    // prologue: stage tile 0 into buffer 0
    gload_lds16(K  + tb + (size_t)(sr + r8) * 512 + h * 64 + cg * 8, &Kl[0][sr][0]);
    gload_lds16(Vt + (size_t)(b * 512 + h * 64 + sr + r8) * T_SEQ + cg * 8, &Vl[0][sr][0]);
    asm volatile("s_waitcnt vmcnt(0)" ::: "memory");
    __syncthreads();

    const int swz = nl & 7;

    for (int kt = 0; kt < 32; ++kt) {
        const int cur = kt & 1;
        short (*Kb)[64] = Kl[cur];
        short (*Vb)[64] = Vl[cur];

        // issue next tile's DMA (lands before next iteration's barrier)
        if (kt < 31) {
            short (*Kn)[64] = Kl[cur ^ 1];
            short (*Vn)[64] = Vl[cur ^ 1];
            gload_lds16(K  + tb + (size_t)((kt + 1) * 64 + sr + r8) * 512 + h * 64 + cg * 8, &Kn[sr][0]);
            gload_lds16(Vt + (size_t)(b * 512 + h * 64 + sr + r8) * T_SEQ + (size_t)(kt + 1) * 64 + cg * 8, &Vn[sr][0]);
        }

        // scores S^T[kv][q] (log2 domain); mask bias enters as MFMA C-input
        float p[4][4];
        #pragma unroll
        for (int s = 0; s < 4; ++s) {
            const bf16x8 k0 = *reinterpret_cast<const bf16x8*>(&Kb[s * 16 + nl][(quad ^ swz) * 8]);
            const bf16x8 k1 = *reinterpret_cast<const bf16x8*>(&Kb[s * 16 + nl][((4 + quad) ^ swz) * 8]);
            const float4 bb = *reinterpret_cast<const float4*>(
                &biasB[kt * 64 + s * 16 + quad * 4]);
            f32x4 z = {bb.x, bb.y, bb.z, bb.w};
            z = __builtin_amdgcn_mfma_f32_16x16x32_bf16(k0, qb0, z, 0, 0, 0);
            z = __builtin_amdgcn_mfma_f32_16x16x32_bf16(k1, qb1, z, 0, 0, 0);
            p[s][0] = fexp2(z[0]);
            p[s][1] = fexp2(z[1]);
            p[s][2] = fexp2(z[2]);
            p[s][3] = fexp2(z[3]);
            l_run += p[s][0] + p[s][1] + p[s][2] + p[s][3];
        }

        // P -> LDS [q][kv], pitch 64 with 16B-slot XOR (key = nl&7).
        #pragma unroll
        for (int s = 0; s < 4; ++s) {
            int2 pk;
            pk.x = pack2bf(p[s][0], p[s][1]);
            pk.y = pack2bf(p[s][2], p[s][3]);
            const int slot = (2 * s + (quad >> 1)) ^ swz;
            *reinterpret_cast<int2*>(&Pl[w][nl][slot * 8 + (quad & 1) * 4]) = pk;
        }

        // O^T += V^T . P^T (pa read back with the same slot-XOR)
        const bf16x8 pa0 = *reinterpret_cast<const bf16x8*>(&Pl[w][nl][(quad ^ swz) * 8]);
        const bf16x8 pa1 = *reinterpret_cast<const bf16x8*>(&Pl[w][nl][((4 + quad) ^ swz) * 8]);
        __builtin_amdgcn_s_setprio(1);
        #pragma unroll
        for (int sd = 0; sd < 4; ++sd) {
            const bf16x8 v0 = *reinterpret_cast<const bf16x8*>(&Vb[sd * 16 + nl][(quad ^ swz) * 8]);
            const bf16x8 v1 = *reinterpret_cast<const bf16x8*>(&Vb[sd * 16 + nl][((4 + quad) ^ swz) * 8]);
            oacc[sd] = __builtin_amdgcn_mfma_f32_16x16x32_bf16(v0, pa0, oacc[sd], 0, 0, 0);
            oacc[sd] = __builtin_amdgcn_mfma_f32_16x16x32_bf16(v1, pa1, oacc[sd], 0, 0, 0);
        }
        __builtin_amdgcn_s_setprio(0);

        // drain this iteration's DMA, release buffers
        asm volatile("s_waitcnt vmcnt(0)" ::: "memory");
        __syncthreads();
    }

    // epilogue: reduce l across the 4 kv-quadrant lanes ONCE, then store
    l_run += __shfl_xor(l_run, 16);
    l_run += __shfl_xor(l_run, 32);
    const float inv = 1.0f / l_run;
    unsigned short* ob = AO + tb + (size_t)(qt * 128 + w * 16 + nl) * 512 + h * 64 + quad * 4;
    #pragma unroll
    for (int sd = 0; sd < 4; ++sd) {
        ushort4 ov;
        ov.x = f2b(oacc[sd][0] * inv);
        ov.y = f2b(oacc[sd][1] * inv);
        ov.z = f2b(oacc[sd][2] * inv);
        ov.w = f2b(oacc[sd][3] * inv);
        *reinterpret_cast<ushort4*>(ob + sd * 16) = ov;
    }
}

extern "C" void kernel_launch(void* const* d_in, const int* in_sizes, int n_in,
                              void* d_out, int out_size, void* d_ws, size_t ws_size,
                              hipStream_t stream) {
    const float* skel = (const float*)d_in[0];
    const float* sens = (const float*)d_in[1];
    const int* mask_skel = (const int*)d_in[2];
    const int* mask_sens = (const int*)d_in[3];
    const float* Wq_s2e = (const float*)d_in[4];
    const float* Wk_e   = (const float*)d_in[5];
    const float* Wv_e   = (const float*)d_in[6];
    const float* Wq_e2s = (const float*)d_in[7];
    const float* Wk_s   = (const float*)d_in[8];
    const float* Wv_s   = (const float*)d_in[9];
    const float* Wo_s   = (const float*)d_in[10];
    const float* Wo_e   = (const float*)d_in[11];
    float* out = (float*)d_out;   // fp32: [e2s (4M)][s2e (4M)]

    unsigned short* Q1 = (unsigned short*)d_ws;    // dir0 Q / AO (aliased)
    unsigned short* K1 = Q1 + N_TOK;
    unsigned short* V1 = K1 + N_TOK;               // Vt

    const bool big = ws_size >= (size_t)6 * N_TOK * sizeof(unsigned short);

    if (big) {
        unsigned short* Q2 = V1 + N_TOK;
        unsigned short* K2 = Q2 + N_TOK;
        unsigned short* V2 = K2 + N_TOK;
        // bf16+bias scratch lives in d_out (dead until out_fused, stream order)
        unsigned short* SC  = (unsigned short*)d_out;
        unsigned short* skb = SC;
        unsigned short* snb = SC + N_TOK;
        unsigned short* wb  = SC + 2 * (size_t)N_TOK;
        float* biasS = (float*)(SC + 2 * (size_t)N_TOK + 6 * W_ELEM);
        float* bias0 = biasS;                 // dir0 <- mask_sens
        float* bias1 = biasS + 4 * T_SEQ;     // dir1 <- mask_skel
        to_bf16<<<dim3(4872), 256, 0, stream>>>(
            skel, sens, Wq_s2e, Wk_e, Wv_e, Wq_e2s, Wk_s, Wv_s,
            mask_sens, mask_skel, SC, biasS);
        // dir0 = s2e (out slot 1), dir1 = e2s (out slot 0)
        proj_fused<<<dim3(1536), 256, 0, stream>>>(
            skb, snb, wb, Q1, K1, V1, Q2, K2, V2);
        attn_mfma<<<dim3(1024), 512, 0, stream>>>(
            Q1, K1, V1, bias0, Q1,
            Q2, K2, V2, bias1, Q2);
        // Wo -> bf16 into dead K1 region, then fused output projections
        wo_bf16<<<dim3(256), 256, 0, stream>>>(Wo_e, Wo_s, K1);
        out_fused<<<dim3(512), 256, 0, stream>>>(
            Q1, K1, out + N_TOK, Q2, K1 + W_ELEM, out);
    } else {
        // sequential fallback: reuse the 3-buffer workspace per direction.
        // bias scratch in the e2s half of out (overwritten by the LAST
        // out_proj, after its final use).
        float* bias0 = out;                   // dir0 <- mask_sens
        float* bias1 = out + 8192;            // dir1 <- mask_skel
        prep_bias<<<dim3(8), 256, 0, stream>>>(mask_sens, mask_skel, bias0);
        proj_all<<<dim3(8, 128, 3), 256, 0, stream>>>(
            skel, sens, Wq_s2e, Wk_e, Wv_e, Wq_e2s, Wk_s, Wv_s,
            Q1, K1, V1, Q1, K1, V1, 0);
        attn_mfma<<<dim3(512), 512, 0, stream>>>(
            Q1, K1, V1, bias0, Q1, Q1, K1, V1, bias0, Q1);
        out_proj<<<dim3(8, 128, 1), 256, 0, stream>>>(
            Q1, Wo_e, out + N_TOK, Q1, Wo_s, out, 0);
        proj_all<<<dim3(8, 128, 3), 256, 0, stream>>>(
            skel, sens, Wq_s2e, Wk_e, Wv_e, Wq_e2s, Wk_s, Wv_s,
            Q1, K1, V1, Q1, K1, V1, 3);
        attn_mfma<<<dim3(512), 512, 0, stream>>>(
            Q1, K1, V1, bias1, Q1, Q1, K1, V1, bias1, Q1);
        out_proj<<<dim3(8, 128, 1), 256, 0, stream>>>(
            Q1, Wo_s, out, Q1, Wo_s, out, 1);
    }
}